// Round 5
// baseline (2422.718 us; speedup 1.0000x reference)
//
#include <hip/hip_runtime.h>

#define LN_EPS 1e-6f

static __device__ __forceinline__ float bf2f(unsigned short u) {
    union { unsigned int i; float f; } v; v.i = ((unsigned int)u) << 16; return v.f;
}
static __device__ __forceinline__ unsigned short f2bf(float f) {
    union { float ff; unsigned int i; } v; v.ff = f;
    return (unsigned short)((v.i + 0x7FFFu + ((v.i >> 16) & 1u)) >> 16);  // RNE
}
static __device__ __forceinline__ float wave_sum(float v) {
    #pragma unroll
    for (int o = 32; o >= 1; o >>= 1) v += __shfl_xor(v, o);
    return v;
}
static __device__ __forceinline__ float wave_max(float v) {
    #pragma unroll
    for (int o = 32; o >= 1; o >>= 1) v = fmaxf(v, __shfl_xor(v, o));
    return v;
}

// ---------------- kernel: mod = silu(time) @ mod_w + mod_b  (8 x 3072) ----------------
__global__ __launch_bounds__(256) void mod_kernel(const float* __restrict__ timep,
                                                  const float* __restrict__ mod_w,
                                                  const float* __restrict__ mod_b,
                                                  float* __restrict__ mod) {
    __shared__ float st[1024];
    int b = blockIdx.x / 12;
    int j = (blockIdx.x % 12) * 256 + threadIdx.x;
    for (int i = threadIdx.x; i < 1024; i += 256) {
        float t = timep[b * 1024 + i];
        st[i] = t / (1.0f + __expf(-t));   // silu
    }
    __syncthreads();
    float acc = mod_b[j];
    for (int i = 0; i < 1024; ++i) acc = fmaf(st[i], mod_w[(size_t)i * 3072 + j], acc);
    mod[b * 3072 + j] = acc;
}

// ---------------- kernel: h = LN(x) * (scale+1) + shift  -> bf16 (into ws hbuf) ----------------
__global__ __launch_bounds__(256) void ln_mod_kernel(const float* __restrict__ x,
                                                     const float* __restrict__ mod,
                                                     unsigned short* __restrict__ h) {
    __shared__ float red[8];
    int row = blockIdx.x;              // b*1024 + t
    int b = row >> 10;
    const float4 v = reinterpret_cast<const float4*>(x + (size_t)row * 1024)[threadIdx.x];
    float s  = v.x + v.y + v.z + v.w;
    float ss = v.x * v.x + v.y * v.y + v.z * v.z + v.w * v.w;
    #pragma unroll
    for (int o = 32; o >= 1; o >>= 1) { s += __shfl_xor(s, o); ss += __shfl_xor(ss, o); }
    int wid = threadIdx.x >> 6, lane = threadIdx.x & 63;
    if (lane == 0) { red[wid] = s; red[4 + wid] = ss; }
    __syncthreads();
    float mean = (red[0] + red[1] + red[2] + red[3]) * (1.0f / 1024.0f);
    float var  = (red[4] + red[5] + red[6] + red[7]) * (1.0f / 1024.0f) - mean * mean;
    float rstd = rsqrtf(var + LN_EPS);
    int d = threadIdx.x * 4;
    const float* mb = mod + b * 3072;
    float4 shf = *reinterpret_cast<const float4*>(mb + d);          // shift = mod[:, :1024]
    float4 scl = *reinterpret_cast<const float4*>(mb + 1024 + d);   // scale = mod[:, 1024:2048]
    ushort4 o;
    o.x = f2bf((v.x - mean) * rstd * (scl.x + 1.0f) + shf.x);
    o.y = f2bf((v.y - mean) * rstd * (scl.y + 1.0f) + shf.y);
    o.z = f2bf((v.z - mean) * rstd * (scl.z + 1.0f) + shf.z);
    o.w = f2bf((v.w - mean) * rstd * (scl.w + 1.0f) + shf.w);
    reinterpret_cast<ushort4*>(h + (size_t)row * 1024)[threadIdx.x] = o;
}

// ---------------- kernel: qkv GEMM via VALU fp32, scatter to q/k/v (B,H,T,64) ----------------
__global__ __launch_bounds__(256) void gemm_qkv_valu(const unsigned short* __restrict__ A,
                                                     const float* __restrict__ B,
                                                     unsigned short* __restrict__ qb,
                                                     unsigned short* __restrict__ kb,
                                                     unsigned short* __restrict__ vb) {
    __shared__ float As[64][33];
    __shared__ float Bs[32][65];
    const int n0 = blockIdx.x * 64;
    const int m0 = blockIdx.y * 64;
    const int tid = threadIdx.x;
    const int tx = tid & 15, ty = tid >> 4;    // 16x16 thread grid, 4x4 outputs each
    float acc[4][4] = {};
    for (int k0 = 0; k0 < 1024; k0 += 32) {
        __syncthreads();
        for (int idx = tid; idx < 2048; idx += 256) {
            int r = idx >> 5, c = idx & 31;
            As[r][c] = bf2f(A[(size_t)(m0 + r) * 1024 + k0 + c]);
        }
        for (int idx = tid; idx < 2048; idx += 256) {
            int r = idx >> 6, c = idx & 63;
            Bs[r][c] = B[(size_t)(k0 + r) * 3072 + n0 + c];
        }
        __syncthreads();
        #pragma unroll 8
        for (int k = 0; k < 32; ++k) {
            float a0 = As[ty * 4 + 0][k], a1 = As[ty * 4 + 1][k];
            float a2 = As[ty * 4 + 2][k], a3 = As[ty * 4 + 3][k];
            float b0 = Bs[k][tx * 4 + 0], b1 = Bs[k][tx * 4 + 1];
            float b2 = Bs[k][tx * 4 + 2], b3 = Bs[k][tx * 4 + 3];
            acc[0][0] = fmaf(a0, b0, acc[0][0]); acc[0][1] = fmaf(a0, b1, acc[0][1]);
            acc[0][2] = fmaf(a0, b2, acc[0][2]); acc[0][3] = fmaf(a0, b3, acc[0][3]);
            acc[1][0] = fmaf(a1, b0, acc[1][0]); acc[1][1] = fmaf(a1, b1, acc[1][1]);
            acc[1][2] = fmaf(a1, b2, acc[1][2]); acc[1][3] = fmaf(a1, b3, acc[1][3]);
            acc[2][0] = fmaf(a2, b0, acc[2][0]); acc[2][1] = fmaf(a2, b1, acc[2][1]);
            acc[2][2] = fmaf(a2, b2, acc[2][2]); acc[2][3] = fmaf(a2, b3, acc[2][3]);
            acc[3][0] = fmaf(a3, b0, acc[3][0]); acc[3][1] = fmaf(a3, b1, acc[3][1]);
            acc[3][2] = fmaf(a3, b2, acc[3][2]); acc[3][3] = fmaf(a3, b3, acc[3][3]);
        }
    }
    #pragma unroll
    for (int j = 0; j < 4; ++j) {
        int col = n0 + tx * 4 + j;
        int which = col >> 10, rem = col & 1023;
        int hd = rem >> 6, ei = rem & 63;
        unsigned short* dst = which == 0 ? qb : (which == 1 ? kb : vb);
        #pragma unroll
        for (int i = 0; i < 4; ++i) {
            int row = m0 + ty * 4 + i;
            int bb = row >> 10, t = row & 1023;
            dst[(((size_t)(bb * 16 + hd) * 1024 + t) << 6) | ei] = f2bf(acc[i][j]);
        }
    }
}

// ---------------- kernel: per-row (e=64) LN + RoPE on q,k in place ----------------
__global__ __launch_bounds__(256) void lnrope_kernel(unsigned short* __restrict__ qb,
                                                     unsigned short* __restrict__ kb,
                                                     const float* __restrict__ qw,
                                                     const float* __restrict__ kw,
                                                     const float* __restrict__ pos) {
    int gw = blockIdx.x * 4 + (threadIdx.x >> 6);   // global wave id in [0, 2*131072)
    int lane = threadIdx.x & 63;
    int half = gw >> 17;                            // 0 = q, 1 = k
    int row = gw & 131071;                          // (b*16+h)*1024 + t
    unsigned short* buf = half ? kb : qb;
    const float* w = half ? kw : qw;
    int t = row & 1023;
    size_t idx = (size_t)row * 64 + lane;
    float xv = bf2f(buf[idx]);
    float mean = wave_sum(xv) * (1.0f / 64.0f);
    float d = xv - mean;
    float var = wave_sum(d * d) * (1.0f / 64.0f);
    float y = d * rsqrtf(var + LN_EPS) * w[lane];
    // rope: lanes 0..31 are the rotated half; pos flat = t*32 + lane (even=cos, odd=sin)
    float pv = (lane < 32) ? pos[t * 32 + lane] : 0.0f;
    float po = __shfl_xor(pv, 1);
    float py = __shfl_xor(y, 1);
    float res = y;
    if (lane < 32)
        res = ((lane & 1) == 0) ? (y * pv - py * po)    // x0' = x0*cos - x1*sin
                                : (y * po + py * pv);   // x1' = x1*cos + x0*sin
    buf[idx] = f2bf(res);
}

// ---------------- kernel: attention, two-pass, per (b,h) / 16 q-rows per block ----------------
__global__ __launch_bounds__(256) void attn_kernel(const unsigned short* __restrict__ qb,
                                                   const unsigned short* __restrict__ kb,
                                                   const unsigned short* __restrict__ vb,
                                                   unsigned short* __restrict__ ob) {
    __shared__ float qs[16][64];
    __shared__ float kt[64][65];            // stride 65 -> bank-conflict-free column reads
    __shared__ unsigned short sc[16][1024]; // bf16 scores / probs
    const int bh = blockIdx.x >> 6;         // (b*16 + h)
    const int q0 = (blockIdx.x & 63) * 16;
    const int b = bh >> 4, hd = bh & 15;
    const size_t base = (size_t)bh << 16;   // bh * 1024 * 64
    const int tid = threadIdx.x, wid = tid >> 6, lane = tid & 63;
    {   // stage 16 q rows -> fp32 LDS
        int e = tid * 4, r = e >> 6, c = e & 63;
        int2 qv = *reinterpret_cast<const int2*>(qb + base + (size_t)(q0 + r) * 64 + c);
        const unsigned short* qp = reinterpret_cast<const unsigned short*>(&qv);
        #pragma unroll
        for (int i = 0; i < 4; ++i) qs[r][c + i] = bf2f(qp[i]);
    }
    // ---- phase A: scores (each wave owns 4 q rows; lane indexes k) ----
    for (int cc = 0; cc < 16; ++cc) {
        __syncthreads();
        #pragma unroll
        for (int rep = 0; rep < 2; ++rep) {
            int e0 = (tid + rep * 256) * 8, r = e0 >> 6, c = e0 & 63;
            int4 kv = *reinterpret_cast<const int4*>(kb + base + (size_t)(cc * 64 + r) * 64 + c);
            const unsigned short* kp = reinterpret_cast<const unsigned short*>(&kv);
            #pragma unroll
            for (int i = 0; i < 8; ++i) kt[r][c + i] = bf2f(kp[i]);
        }
        __syncthreads();
        float s0 = 0, s1 = 0, s2 = 0, s3 = 0;
        #pragma unroll 8
        for (int j = 0; j < 64; ++j) {
            float kv = kt[lane][j];
            s0 = fmaf(qs[wid * 4 + 0][j], kv, s0);
            s1 = fmaf(qs[wid * 4 + 1][j], kv, s1);
            s2 = fmaf(qs[wid * 4 + 2][j], kv, s2);
            s3 = fmaf(qs[wid * 4 + 3][j], kv, s3);
        }
        sc[wid * 4 + 0][cc * 64 + lane] = f2bf(s0 * 0.125f);
        sc[wid * 4 + 1][cc * 64 + lane] = f2bf(s1 * 0.125f);
        sc[wid * 4 + 2][cc * 64 + lane] = f2bf(s2 * 0.125f);
        sc[wid * 4 + 3][cc * 64 + lane] = f2bf(s3 * 0.125f);
    }
    // ---- phase B: softmax ----
    #pragma unroll
    for (int r = 0; r < 4; ++r) {
        int row = wid * 4 + r;
        float v[16];
        float mx = -1e30f;
        #pragma unroll
        for (int i = 0; i < 16; ++i) { v[i] = bf2f(sc[row][lane + 64 * i]); mx = fmaxf(mx, v[i]); }
        mx = wave_max(mx);
        float sum = 0;
        #pragma unroll
        for (int i = 0; i < 16; ++i) { v[i] = __expf(v[i] - mx); sum += v[i]; }
        sum = wave_sum(sum);
        float inv = 1.0f / sum;
        #pragma unroll
        for (int i = 0; i < 16; ++i) sc[row][lane + 64 * i] = f2bf(v[i] * inv);
    }
    // ---- phase C: o = p @ V ----
    float oa0 = 0, oa1 = 0, oa2 = 0, oa3 = 0;
    for (int cc = 0; cc < 16; ++cc) {
        __syncthreads();
        #pragma unroll
        for (int rep = 0; rep < 2; ++rep) {
            int e0 = (tid + rep * 256) * 8, r = e0 >> 6, c = e0 & 63;
            int4 kv = *reinterpret_cast<const int4*>(vb + base + (size_t)(cc * 64 + r) * 64 + c);
            const unsigned short* kp = reinterpret_cast<const unsigned short*>(&kv);
            #pragma unroll
            for (int i = 0; i < 8; ++i) kt[r][c + i] = bf2f(kp[i]);
        }
        __syncthreads();
        #pragma unroll 8
        for (int k = 0; k < 64; ++k) {
            float vv = kt[k][lane];
            oa0 = fmaf(bf2f(sc[wid * 4 + 0][cc * 64 + k]), vv, oa0);
            oa1 = fmaf(bf2f(sc[wid * 4 + 1][cc * 64 + k]), vv, oa1);
            oa2 = fmaf(bf2f(sc[wid * 4 + 2][cc * 64 + k]), vv, oa2);
            oa3 = fmaf(bf2f(sc[wid * 4 + 3][cc * 64 + k]), vv, oa3);
        }
    }
    // write o in (B, T, H*64) layout for the output GEMM
    size_t orow = (size_t)(b * 1024 + q0 + wid * 4) * 1024 + hd * 64 + lane;
    ob[orow]        = f2bf(oa0);
    ob[orow + 1024] = f2bf(oa1);
    ob[orow + 2048] = f2bf(oa2);
    ob[orow + 3072] = f2bf(oa3);
}

// ---------------- kernel: out GEMM via VALU fp32, fused gate, FLOAT32 output ----------------
__global__ __launch_bounds__(256) void gemm_out_valu(const unsigned short* __restrict__ A,
                                                     const float* __restrict__ B,
                                                     const float* __restrict__ mod,
                                                     float* __restrict__ out) {
    __shared__ float As[64][33];
    __shared__ float Bs[32][65];
    const int n0 = blockIdx.x * 64;
    const int m0 = blockIdx.y * 64;
    const int tid = threadIdx.x;
    const int tx = tid & 15, ty = tid >> 4;
    float acc[4][4] = {};
    for (int k0 = 0; k0 < 1024; k0 += 32) {
        __syncthreads();
        for (int idx = tid; idx < 2048; idx += 256) {
            int r = idx >> 5, c = idx & 31;
            As[r][c] = bf2f(A[(size_t)(m0 + r) * 1024 + k0 + c]);
        }
        for (int idx = tid; idx < 2048; idx += 256) {
            int r = idx >> 6, c = idx & 63;
            Bs[r][c] = B[(size_t)(k0 + r) * 1024 + n0 + c];
        }
        __syncthreads();
        #pragma unroll 8
        for (int k = 0; k < 32; ++k) {
            float a0 = As[ty * 4 + 0][k], a1 = As[ty * 4 + 1][k];
            float a2 = As[ty * 4 + 2][k], a3 = As[ty * 4 + 3][k];
            float b0 = Bs[k][tx * 4 + 0], b1 = Bs[k][tx * 4 + 1];
            float b2 = Bs[k][tx * 4 + 2], b3 = Bs[k][tx * 4 + 3];
            acc[0][0] = fmaf(a0, b0, acc[0][0]); acc[0][1] = fmaf(a0, b1, acc[0][1]);
            acc[0][2] = fmaf(a0, b2, acc[0][2]); acc[0][3] = fmaf(a0, b3, acc[0][3]);
            acc[1][0] = fmaf(a1, b0, acc[1][0]); acc[1][1] = fmaf(a1, b1, acc[1][1]);
            acc[1][2] = fmaf(a1, b2, acc[1][2]); acc[1][3] = fmaf(a1, b3, acc[1][3]);
            acc[2][0] = fmaf(a2, b0, acc[2][0]); acc[2][1] = fmaf(a2, b1, acc[2][1]);
            acc[2][2] = fmaf(a2, b2, acc[2][2]); acc[2][3] = fmaf(a2, b3, acc[2][3]);
            acc[3][0] = fmaf(a3, b0, acc[3][0]); acc[3][1] = fmaf(a3, b1, acc[3][1]);
            acc[3][2] = fmaf(a3, b2, acc[3][2]); acc[3][3] = fmaf(a3, b3, acc[3][3]);
        }
    }
    #pragma unroll
    for (int j = 0; j < 4; ++j) {
        int col = n0 + tx * 4 + j;
        #pragma unroll
        for (int i = 0; i < 4; ++i) {
            int row = m0 + ty * 4 + i;
            int bb = row >> 10;
            float g = mod[bb * 3072 + 2048 + col];   // gate = mod[:, 2048:]
            out[(size_t)row * 1024 + col] = acc[i][j] * g;   // FLOAT32 store
        }
    }
}

extern "C" void kernel_launch(void* const* d_in, const int* in_sizes, int n_in,
                              void* d_out, int out_size, void* d_ws, size_t ws_size,
                              hipStream_t stream) {
    const float* x      = (const float*)d_in[0];   // (8,1024,1024)
    const float* timep  = (const float*)d_in[1];   // (8,1,1024)
    const float* pos    = (const float*)d_in[2];   // (1024,16,2)
    const float* mod_w  = (const float*)d_in[3];   // (1024,3072)
    const float* mod_b  = (const float*)d_in[4];   // (3072,)
    const float* w_qkv  = (const float*)d_in[5];   // (1024,3072)
    const float* w_out  = (const float*)d_in[6];   // (1024,1024)
    const float* qw     = (const float*)d_in[7];   // (64,)
    const float* kw     = (const float*)d_in[8];   // (64,)
    float* outp = (float*)d_out;                   // FLOAT32 (8,1024,1024) = 33.5 MB

    // workspace layout (peak ~64.1 MB; rounds 1/2 proved >=75.5 MB usable):
    char* ws = (char*)d_ws;
    float*          modbuf = (float*)ws;                         // 98304 B
    unsigned short* hbuf   = (unsigned short*)(ws + 98304);      // 16 MB (h, then reused for o)
    unsigned short* qbuf   = hbuf + 8388608;                     // 16 MB
    unsigned short* kbuf   = qbuf + 8388608;                     // 16 MB
    unsigned short* vbuf   = kbuf + 8388608;                     // 16 MB
    unsigned short* obuf   = hbuf;                               // h dead after gemm_qkv

    mod_kernel<<<96, 256, 0, stream>>>(timep, mod_w, mod_b, modbuf);
    ln_mod_kernel<<<8192, 256, 0, stream>>>(x, modbuf, hbuf);
    gemm_qkv_valu<<<dim3(48, 128), 256, 0, stream>>>(hbuf, w_qkv, qbuf, kbuf, vbuf);
    lnrope_kernel<<<65536, 256, 0, stream>>>(qbuf, kbuf, qw, kw, pos);
    attn_kernel<<<8192, 256, 0, stream>>>(qbuf, kbuf, vbuf, obuf);
    gemm_out_valu<<<dim3(16, 128), 256, 0, stream>>>(obuf, w_out, modbuf, outp);
}

// Round 6
// 1318.727 us; speedup vs baseline: 1.8372x; 1.8372x over previous
//
#include <hip/hip_runtime.h>

typedef short bf16x8 __attribute__((ext_vector_type(8)));
typedef float f32x4 __attribute__((ext_vector_type(4)));

#define LN_EPS 1e-6f

static __device__ __forceinline__ float bf2f(unsigned short u) {
    union { unsigned int i; float f; } v; v.i = ((unsigned int)u) << 16; return v.f;
}
static __device__ __forceinline__ unsigned short f2bf(float f) {
    union { float ff; unsigned int i; } v; v.ff = f;
    return (unsigned short)((v.i + 0x7FFFu + ((v.i >> 16) & 1u)) >> 16);  // RNE
}
static __device__ __forceinline__ float wave_sum(float v) {
    #pragma unroll
    for (int o = 32; o >= 1; o >>= 1) v += __shfl_xor(v, o);
    return v;
}
static __device__ __forceinline__ float wave_max(float v) {
    #pragma unroll
    for (int o = 32; o >= 1; o >>= 1) v = fmaxf(v, __shfl_xor(v, o));
    return v;
}

// ---------------- kernel: mod = silu(time) @ mod_w + mod_b  (8 x 3072) ----------------
__global__ __launch_bounds__(256) void mod_kernel(const float* __restrict__ timep,
                                                  const float* __restrict__ mod_w,
                                                  const float* __restrict__ mod_b,
                                                  float* __restrict__ mod) {
    __shared__ float st[1024];
    int b = blockIdx.x / 12;
    int j = (blockIdx.x % 12) * 256 + threadIdx.x;
    for (int i = threadIdx.x; i < 1024; i += 256) {
        float t = timep[b * 1024 + i];
        st[i] = t / (1.0f + __expf(-t));   // silu
    }
    __syncthreads();
    float acc = mod_b[j];
    for (int i = 0; i < 1024; ++i) acc = fmaf(st[i], mod_w[(size_t)i * 3072 + j], acc);
    mod[b * 3072 + j] = acc;
}

// ---------------- kernel: h = LN(x) * (scale+1) + shift  -> bf16 ----------------
__global__ __launch_bounds__(256) void ln_mod_kernel(const float* __restrict__ x,
                                                     const float* __restrict__ mod,
                                                     unsigned short* __restrict__ h) {
    __shared__ float red[8];
    int row = blockIdx.x;              // b*1024 + t
    int b = row >> 10;
    const float4 v = reinterpret_cast<const float4*>(x + (size_t)row * 1024)[threadIdx.x];
    float s  = v.x + v.y + v.z + v.w;
    float ss = v.x * v.x + v.y * v.y + v.z * v.z + v.w * v.w;
    #pragma unroll
    for (int o = 32; o >= 1; o >>= 1) { s += __shfl_xor(s, o); ss += __shfl_xor(ss, o); }
    int wid = threadIdx.x >> 6, lane = threadIdx.x & 63;
    if (lane == 0) { red[wid] = s; red[4 + wid] = ss; }
    __syncthreads();
    float mean = (red[0] + red[1] + red[2] + red[3]) * (1.0f / 1024.0f);
    float var  = (red[4] + red[5] + red[6] + red[7]) * (1.0f / 1024.0f) - mean * mean;
    float rstd = rsqrtf(var + LN_EPS);
    int d = threadIdx.x * 4;
    const float* mb = mod + b * 3072;
    float4 shf = *reinterpret_cast<const float4*>(mb + d);          // shift
    float4 scl = *reinterpret_cast<const float4*>(mb + 1024 + d);   // scale
    ushort4 o;
    o.x = f2bf((v.x - mean) * rstd * (scl.x + 1.0f) + shf.x);
    o.y = f2bf((v.y - mean) * rstd * (scl.y + 1.0f) + shf.y);
    o.z = f2bf((v.z - mean) * rstd * (scl.z + 1.0f) + shf.z);
    o.w = f2bf((v.w - mean) * rstd * (scl.w + 1.0f) + shf.w);
    reinterpret_cast<ushort4*>(h + (size_t)row * 1024)[threadIdx.x] = o;
}

// ---------------- kernel: fp32 [R][C] -> bf16 transposed [C][R] ----------------
__global__ __launch_bounds__(256) void transpose_cvt_kernel(const float* __restrict__ src,
                                                            unsigned short* __restrict__ dst,
                                                            int R, int C) {
    __shared__ unsigned short t[32][33];
    int c0 = blockIdx.x * 32, r0 = blockIdx.y * 32;
    int tx = threadIdx.x & 31, ty = threadIdx.x >> 5;   // 8 rows per pass
    #pragma unroll
    for (int i = 0; i < 4; ++i) {
        int r = ty + i * 8;
        t[r][tx] = f2bf(src[(size_t)(r0 + r) * C + c0 + tx]);
    }
    __syncthreads();
    #pragma unroll
    for (int i = 0; i < 4; ++i) {
        int c = ty + i * 8;
        dst[(size_t)(c0 + c) * R + r0 + tx] = t[tx][c];
    }
}

// ---------------- MFMA GEMM main loop: C[128x128] tile = A[128xK] @ Bt[128xK]^T ----------------
// A, Bt row-major bf16 with K=1024. LDS tiles [128 rows][64 k] with XOR seg-swizzle
// (seg' = seg ^ (row&7), seg = 16B unit) -> conflict-free ds_read_b128.
static __device__ __forceinline__ void gemm_mainloop(const unsigned short* __restrict__ A,
                                                     const unsigned short* __restrict__ Bt,
                                                     int m0, int n0,
                                                     unsigned short* As, unsigned short* Bs,
                                                     f32x4 (&acc)[4][4]) {
    const int tid = threadIdx.x;
    const int wid = tid >> 6, lane = tid & 63;
    const int wr = wid >> 1, wc = wid & 1;
    const int lr = lane & 15, lks = lane >> 4;   // frag row, k-seg
    const int srow = tid >> 3;                    // staging row 0..31 (per issue group)
    const int sseg = tid & 7;                     // staging 16B-seg 0..7
    int4 av[4], bv[4];
    #pragma unroll
    for (int i = 0; i < 4; ++i) {
        int r = i * 32 + srow;
        av[i] = *reinterpret_cast<const int4*>(A  + (size_t)(m0 + r) * 1024 + sseg * 8);
        bv[i] = *reinterpret_cast<const int4*>(Bt + (size_t)(n0 + r) * 1024 + sseg * 8);
    }
    for (int k0 = 0; k0 < 1024; k0 += 64) {
        __syncthreads();   // previous compute done reading LDS
        #pragma unroll
        for (int i = 0; i < 4; ++i) {
            int r = i * 32 + srow;
            int ss = sseg ^ (r & 7);
            *reinterpret_cast<int4*>(As + r * 64 + ss * 8) = av[i];
            *reinterpret_cast<int4*>(Bs + r * 64 + ss * 8) = bv[i];
        }
        __syncthreads();   // writes visible
        if (k0 + 64 < 1024) {   // prefetch next tile during compute
            #pragma unroll
            for (int i = 0; i < 4; ++i) {
                int r = i * 32 + srow;
                av[i] = *reinterpret_cast<const int4*>(A  + (size_t)(m0 + r) * 1024 + k0 + 64 + sseg * 8);
                bv[i] = *reinterpret_cast<const int4*>(Bt + (size_t)(n0 + r) * 1024 + k0 + 64 + sseg * 8);
            }
        }
        #pragma unroll
        for (int ks = 0; ks < 2; ++ks) {
            bf16x8 af[4], bfr[4];
            #pragma unroll
            for (int mi = 0; mi < 4; ++mi) {
                int row = wr * 64 + mi * 16 + lr;
                int ss = (ks * 4 + lks) ^ (row & 7);
                af[mi] = *reinterpret_cast<const bf16x8*>(As + row * 64 + ss * 8);
            }
            #pragma unroll
            for (int ni = 0; ni < 4; ++ni) {
                int row = wc * 64 + ni * 16 + lr;
                int ss = (ks * 4 + lks) ^ (row & 7);
                bfr[ni] = *reinterpret_cast<const bf16x8*>(Bs + row * 64 + ss * 8);
            }
            #pragma unroll
            for (int mi = 0; mi < 4; ++mi)
                #pragma unroll
                for (int ni = 0; ni < 4; ++ni)
                    acc[mi][ni] = __builtin_amdgcn_mfma_f32_16x16x32_bf16(af[mi], bfr[ni], acc[mi][ni], 0, 0, 0);
        }
    }
}

// ---------------- kernel: qkv GEMM (8192x3072x1024 MFMA), scatter to q/k/v (B,H,T,64) ----------------
__global__ __launch_bounds__(256) void gemm_qkv_mfma(const unsigned short* __restrict__ A,
                                                     const unsigned short* __restrict__ Bt,
                                                     unsigned short* __restrict__ qb,
                                                     unsigned short* __restrict__ kb,
                                                     unsigned short* __restrict__ vb) {
    __shared__ unsigned short As[128 * 64];
    __shared__ unsigned short Bs[128 * 64];
    const int n0 = blockIdx.x * 128;
    const int m0 = blockIdx.y * 128;
    const int wid = threadIdx.x >> 6, lane = threadIdx.x & 63;
    const int wr = wid >> 1, wc = wid & 1;
    f32x4 acc[4][4] = {};
    gemm_mainloop(A, Bt, m0, n0, As, Bs, acc);
    // C/D layout: col = lane&15, row = (lane>>4)*4 + reg
    #pragma unroll
    for (int mi = 0; mi < 4; ++mi)
    #pragma unroll
    for (int ni = 0; ni < 4; ++ni) {
        int col = n0 + wc * 64 + ni * 16 + (lane & 15);
        int which = col >> 10, rem = col & 1023;
        int hd = rem >> 6, ei = rem & 63;
        unsigned short* dst = which == 0 ? qb : (which == 1 ? kb : vb);
        #pragma unroll
        for (int r = 0; r < 4; ++r) {
            int row = m0 + wr * 64 + mi * 16 + (lane >> 4) * 4 + r;
            int bb = row >> 10, t = row & 1023;
            dst[(((size_t)(bb * 16 + hd) * 1024 + t) << 6) | ei] = f2bf(acc[mi][ni][r]);
        }
    }
}

// ---------------- kernel: out GEMM (8192x1024x1024 MFMA), fused gate, f32 output ----------------
__global__ __launch_bounds__(256) void gemm_out_mfma(const unsigned short* __restrict__ A,
                                                     const unsigned short* __restrict__ Bt,
                                                     const float* __restrict__ mod,
                                                     float* __restrict__ out) {
    __shared__ unsigned short As[128 * 64];
    __shared__ unsigned short Bs[128 * 64];
    const int n0 = blockIdx.x * 128;
    const int m0 = blockIdx.y * 128;
    const int wid = threadIdx.x >> 6, lane = threadIdx.x & 63;
    const int wr = wid >> 1, wc = wid & 1;
    f32x4 acc[4][4] = {};
    gemm_mainloop(A, Bt, m0, n0, As, Bs, acc);
    #pragma unroll
    for (int mi = 0; mi < 4; ++mi)
    #pragma unroll
    for (int ni = 0; ni < 4; ++ni) {
        int col = n0 + wc * 64 + ni * 16 + (lane & 15);
        #pragma unroll
        for (int r = 0; r < 4; ++r) {
            int row = m0 + wr * 64 + mi * 16 + (lane >> 4) * 4 + r;
            int bb = row >> 10;
            float g = mod[bb * 3072 + 2048 + col];   // gate
            out[(size_t)row * 1024 + col] = acc[mi][ni][r] * g;
        }
    }
}

// ---------------- kernel: per-row (e=64) LN + RoPE on q,k in place ----------------
__global__ __launch_bounds__(256) void lnrope_kernel(unsigned short* __restrict__ qb,
                                                     unsigned short* __restrict__ kb,
                                                     const float* __restrict__ qw,
                                                     const float* __restrict__ kw,
                                                     const float* __restrict__ pos) {
    int gw = blockIdx.x * 4 + (threadIdx.x >> 6);
    int lane = threadIdx.x & 63;
    int half = gw >> 17;                            // 0 = q, 1 = k
    int row = gw & 131071;                          // (b*16+h)*1024 + t
    unsigned short* buf = half ? kb : qb;
    const float* w = half ? kw : qw;
    int t = row & 1023;
    size_t idx = (size_t)row * 64 + lane;
    float xv = bf2f(buf[idx]);
    float mean = wave_sum(xv) * (1.0f / 64.0f);
    float d = xv - mean;
    float var = wave_sum(d * d) * (1.0f / 64.0f);
    float y = d * rsqrtf(var + LN_EPS) * w[lane];
    float pv = (lane < 32) ? pos[t * 32 + lane] : 0.0f;
    float po = __shfl_xor(pv, 1);
    float py = __shfl_xor(y, 1);
    float res = y;
    if (lane < 32)
        res = ((lane & 1) == 0) ? (y * pv - py * po)    // x0' = x0*cos - x1*sin
                                : (y * po + py * pv);   // x1' = x1*cos + x0*sin
    buf[idx] = f2bf(res);
}

// ---------------- kernel: attention, two-pass, per (b,h) / 16 q-rows per block ----------------
__global__ __launch_bounds__(256) void attn_kernel(const unsigned short* __restrict__ qb,
                                                   const unsigned short* __restrict__ kb,
                                                   const unsigned short* __restrict__ vb,
                                                   unsigned short* __restrict__ ob) {
    __shared__ float qs[16][64];
    __shared__ float kt[64][65];
    __shared__ unsigned short sc[16][1024];
    const int bh = blockIdx.x >> 6;
    const int q0 = (blockIdx.x & 63) * 16;
    const int b = bh >> 4, hd = bh & 15;
    const size_t base = (size_t)bh << 16;
    const int tid = threadIdx.x, wid = tid >> 6, lane = tid & 63;
    {
        int e = tid * 4, r = e >> 6, c = e & 63;
        int2 qv = *reinterpret_cast<const int2*>(qb + base + (size_t)(q0 + r) * 64 + c);
        const unsigned short* qp = reinterpret_cast<const unsigned short*>(&qv);
        #pragma unroll
        for (int i = 0; i < 4; ++i) qs[r][c + i] = bf2f(qp[i]);
    }
    for (int cc = 0; cc < 16; ++cc) {
        __syncthreads();
        #pragma unroll
        for (int rep = 0; rep < 2; ++rep) {
            int e0 = (tid + rep * 256) * 8, r = e0 >> 6, c = e0 & 63;
            int4 kv = *reinterpret_cast<const int4*>(kb + base + (size_t)(cc * 64 + r) * 64 + c);
            const unsigned short* kp = reinterpret_cast<const unsigned short*>(&kv);
            #pragma unroll
            for (int i = 0; i < 8; ++i) kt[r][c + i] = bf2f(kp[i]);
        }
        __syncthreads();
        float s0 = 0, s1 = 0, s2 = 0, s3 = 0;
        #pragma unroll 8
        for (int j = 0; j < 64; ++j) {
            float kv = kt[lane][j];
            s0 = fmaf(qs[wid * 4 + 0][j], kv, s0);
            s1 = fmaf(qs[wid * 4 + 1][j], kv, s1);
            s2 = fmaf(qs[wid * 4 + 2][j], kv, s2);
            s3 = fmaf(qs[wid * 4 + 3][j], kv, s3);
        }
        sc[wid * 4 + 0][cc * 64 + lane] = f2bf(s0 * 0.125f);
        sc[wid * 4 + 1][cc * 64 + lane] = f2bf(s1 * 0.125f);
        sc[wid * 4 + 2][cc * 64 + lane] = f2bf(s2 * 0.125f);
        sc[wid * 4 + 3][cc * 64 + lane] = f2bf(s3 * 0.125f);
    }
    #pragma unroll
    for (int r = 0; r < 4; ++r) {
        int row = wid * 4 + r;
        float v[16];
        float mx = -1e30f;
        #pragma unroll
        for (int i = 0; i < 16; ++i) { v[i] = bf2f(sc[row][lane + 64 * i]); mx = fmaxf(mx, v[i]); }
        mx = wave_max(mx);
        float sum = 0;
        #pragma unroll
        for (int i = 0; i < 16; ++i) { v[i] = __expf(v[i] - mx); sum += v[i]; }
        sum = wave_sum(sum);
        float inv = 1.0f / sum;
        #pragma unroll
        for (int i = 0; i < 16; ++i) sc[row][lane + 64 * i] = f2bf(v[i] * inv);
    }
    float oa0 = 0, oa1 = 0, oa2 = 0, oa3 = 0;
    for (int cc = 0; cc < 16; ++cc) {
        __syncthreads();
        #pragma unroll
        for (int rep = 0; rep < 2; ++rep) {
            int e0 = (tid + rep * 256) * 8, r = e0 >> 6, c = e0 & 63;
            int4 kv = *reinterpret_cast<const int4*>(vb + base + (size_t)(cc * 64 + r) * 64 + c);
            const unsigned short* kp = reinterpret_cast<const unsigned short*>(&kv);
            #pragma unroll
            for (int i = 0; i < 8; ++i) kt[r][c + i] = bf2f(kp[i]);
        }
        __syncthreads();
        #pragma unroll 8
        for (int k = 0; k < 64; ++k) {
            float vv = kt[k][lane];
            oa0 = fmaf(bf2f(sc[wid * 4 + 0][cc * 64 + k]), vv, oa0);
            oa1 = fmaf(bf2f(sc[wid * 4 + 1][cc * 64 + k]), vv, oa1);
            oa2 = fmaf(bf2f(sc[wid * 4 + 2][cc * 64 + k]), vv, oa2);
            oa3 = fmaf(bf2f(sc[wid * 4 + 3][cc * 64 + k]), vv, oa3);
        }
    }
    size_t orow = (size_t)(b * 1024 + q0 + wid * 4) * 1024 + hd * 64 + lane;
    ob[orow]        = f2bf(oa0);
    ob[orow + 1024] = f2bf(oa1);
    ob[orow + 2048] = f2bf(oa2);
    ob[orow + 3072] = f2bf(oa3);
}

extern "C" void kernel_launch(void* const* d_in, const int* in_sizes, int n_in,
                              void* d_out, int out_size, void* d_ws, size_t ws_size,
                              hipStream_t stream) {
    const float* x      = (const float*)d_in[0];   // (8,1024,1024)
    const float* timep  = (const float*)d_in[1];   // (8,1,1024)
    const float* pos    = (const float*)d_in[2];   // (1024,16,2)
    const float* mod_w  = (const float*)d_in[3];   // (1024,3072)
    const float* mod_b  = (const float*)d_in[4];   // (3072,)
    const float* w_qkv  = (const float*)d_in[5];   // (1024,3072)
    const float* w_out  = (const float*)d_in[6];   // (1024,1024)
    const float* qw     = (const float*)d_in[7];   // (64,)
    const float* kw     = (const float*)d_in[8];   // (64,)
    float* outp = (float*)d_out;                   // f32 (8,1024,1024)

    // workspace layout (75,595,776 B total == round-1-proven footprint):
    char* ws = (char*)d_ws;
    float*          modbuf = (float*)ws;                          // 98304 B
    unsigned short* wqkvT  = (unsigned short*)(ws + 98304);       // bf16 [3072][1024], 6 MB
    unsigned short* woutT  = (unsigned short*)(ws + 6389760);     // bf16 [1024][1024], 2 MB
    unsigned short* hbuf   = (unsigned short*)(ws + 8486912);     // 16 MB (h, then o)
    unsigned short* qbuf   = hbuf + 8388608;                      // 16 MB
    unsigned short* kbuf   = qbuf + 8388608;                      // 16 MB
    unsigned short* vbuf   = kbuf + 8388608;                      // 16 MB
    unsigned short* obuf   = hbuf;                                // h dead after gemm_qkv

    transpose_cvt_kernel<<<dim3(96, 32), 256, 0, stream>>>(w_qkv, wqkvT, 1024, 3072);
    transpose_cvt_kernel<<<dim3(32, 32), 256, 0, stream>>>(w_out, woutT, 1024, 1024);
    mod_kernel<<<96, 256, 0, stream>>>(timep, mod_w, mod_b, modbuf);
    ln_mod_kernel<<<8192, 256, 0, stream>>>(x, modbuf, hbuf);
    gemm_qkv_mfma<<<dim3(24, 64), 256, 0, stream>>>(hbuf, wqkvT, qbuf, kbuf, vbuf);
    lnrope_kernel<<<65536, 256, 0, stream>>>(qbuf, kbuf, qw, kw, pos);
    attn_kernel<<<8192, 256, 0, stream>>>(qbuf, kbuf, vbuf, obuf);
    gemm_out_mfma<<<dim3(8, 64), 256, 0, stream>>>(obuf, woutT, modbuf, outp);
}

// Round 7
// 539.092 us; speedup vs baseline: 4.4941x; 2.4462x over previous
//
#include <hip/hip_runtime.h>

typedef short bf16x8 __attribute__((ext_vector_type(8)));
typedef float f32x4 __attribute__((ext_vector_type(4)));

#define LN_EPS 1e-6f

static __device__ __forceinline__ float bf2f(unsigned short u) {
    union { unsigned int i; float f; } v; v.i = ((unsigned int)u) << 16; return v.f;
}
static __device__ __forceinline__ unsigned short f2bf(float f) {
    union { float ff; unsigned int i; } v; v.ff = f;
    return (unsigned short)((v.i + 0x7FFFu + ((v.i >> 16) & 1u)) >> 16);  // RNE
}
static __device__ __forceinline__ float wave_sum(float v) {
    #pragma unroll
    for (int o = 32; o >= 1; o >>= 1) v += __shfl_xor(v, o);
    return v;
}

// ---------------- kernel: mod = silu(time) @ mod_w + mod_b  (8 x 3072) ----------------
__global__ __launch_bounds__(256) void mod_kernel(const float* __restrict__ timep,
                                                  const float* __restrict__ mod_w,
                                                  const float* __restrict__ mod_b,
                                                  float* __restrict__ mod) {
    __shared__ float st[1024];
    int b = blockIdx.x / 12;
    int j = (blockIdx.x % 12) * 256 + threadIdx.x;
    for (int i = threadIdx.x; i < 1024; i += 256) {
        float t = timep[b * 1024 + i];
        st[i] = t / (1.0f + __expf(-t));   // silu
    }
    __syncthreads();
    float acc = mod_b[j];
    for (int i = 0; i < 1024; ++i) acc = fmaf(st[i], mod_w[(size_t)i * 3072 + j], acc);
    mod[b * 3072 + j] = acc;
}

// ---------------- kernel: h = LN(x) * (scale+1) + shift  -> bf16 ----------------
__global__ __launch_bounds__(256) void ln_mod_kernel(const float* __restrict__ x,
                                                     const float* __restrict__ mod,
                                                     unsigned short* __restrict__ h) {
    __shared__ float red[8];
    int row = blockIdx.x;              // b*1024 + t
    int b = row >> 10;
    const float4 v = reinterpret_cast<const float4*>(x + (size_t)row * 1024)[threadIdx.x];
    float s  = v.x + v.y + v.z + v.w;
    float ss = v.x * v.x + v.y * v.y + v.z * v.z + v.w * v.w;
    #pragma unroll
    for (int o = 32; o >= 1; o >>= 1) { s += __shfl_xor(s, o); ss += __shfl_xor(ss, o); }
    int wid = threadIdx.x >> 6, lane = threadIdx.x & 63;
    if (lane == 0) { red[wid] = s; red[4 + wid] = ss; }
    __syncthreads();
    float mean = (red[0] + red[1] + red[2] + red[3]) * (1.0f / 1024.0f);
    float var  = (red[4] + red[5] + red[6] + red[7]) * (1.0f / 1024.0f) - mean * mean;
    float rstd = rsqrtf(var + LN_EPS);
    int d = threadIdx.x * 4;
    const float* mb = mod + b * 3072;
    float4 shf = *reinterpret_cast<const float4*>(mb + d);          // shift
    float4 scl = *reinterpret_cast<const float4*>(mb + 1024 + d);   // scale
    ushort4 o;
    o.x = f2bf((v.x - mean) * rstd * (scl.x + 1.0f) + shf.x);
    o.y = f2bf((v.y - mean) * rstd * (scl.y + 1.0f) + shf.y);
    o.z = f2bf((v.z - mean) * rstd * (scl.z + 1.0f) + shf.z);
    o.w = f2bf((v.w - mean) * rstd * (scl.w + 1.0f) + shf.w);
    reinterpret_cast<ushort4*>(h + (size_t)row * 1024)[threadIdx.x] = o;
}

// ---------------- kernel: fp32 [R][C] -> bf16 transposed [C][R] ----------------
__global__ __launch_bounds__(256) void transpose_cvt_kernel(const float* __restrict__ src,
                                                            unsigned short* __restrict__ dst,
                                                            int R, int C) {
    __shared__ unsigned short t[32][33];
    int c0 = blockIdx.x * 32, r0 = blockIdx.y * 32;
    int tx = threadIdx.x & 31, ty = threadIdx.x >> 5;
    #pragma unroll
    for (int i = 0; i < 4; ++i) {
        int r = ty + i * 8;
        t[r][tx] = f2bf(src[(size_t)(r0 + r) * C + c0 + tx]);
    }
    __syncthreads();
    #pragma unroll
    for (int i = 0; i < 4; ++i) {
        int c = ty + i * 8;
        dst[(size_t)(c0 + c) * R + r0 + tx] = t[tx][c];
    }
}

// ---------------- MFMA GEMM main loop: C[128x128] tile = A[128xK] @ Bt[128xK]^T ----------------
static __device__ __forceinline__ void gemm_mainloop(const unsigned short* __restrict__ A,
                                                     const unsigned short* __restrict__ Bt,
                                                     int m0, int n0,
                                                     unsigned short* As, unsigned short* Bs,
                                                     f32x4 (&acc)[4][4]) {
    const int tid = threadIdx.x;
    const int wid = tid >> 6, lane = tid & 63;
    const int wr = wid >> 1, wc = wid & 1;
    const int lr = lane & 15, lks = lane >> 4;
    const int srow = tid >> 3;
    const int sseg = tid & 7;
    int4 av[4], bv[4];
    #pragma unroll
    for (int i = 0; i < 4; ++i) {
        int r = i * 32 + srow;
        av[i] = *reinterpret_cast<const int4*>(A  + (size_t)(m0 + r) * 1024 + sseg * 8);
        bv[i] = *reinterpret_cast<const int4*>(Bt + (size_t)(n0 + r) * 1024 + sseg * 8);
    }
    for (int k0 = 0; k0 < 1024; k0 += 64) {
        __syncthreads();
        #pragma unroll
        for (int i = 0; i < 4; ++i) {
            int r = i * 32 + srow;
            int ss = sseg ^ (r & 7);
            *reinterpret_cast<int4*>(As + r * 64 + ss * 8) = av[i];
            *reinterpret_cast<int4*>(Bs + r * 64 + ss * 8) = bv[i];
        }
        __syncthreads();
        if (k0 + 64 < 1024) {
            #pragma unroll
            for (int i = 0; i < 4; ++i) {
                int r = i * 32 + srow;
                av[i] = *reinterpret_cast<const int4*>(A  + (size_t)(m0 + r) * 1024 + k0 + 64 + sseg * 8);
                bv[i] = *reinterpret_cast<const int4*>(Bt + (size_t)(n0 + r) * 1024 + k0 + 64 + sseg * 8);
            }
        }
        #pragma unroll
        for (int ks = 0; ks < 2; ++ks) {
            bf16x8 af[4], bfr[4];
            #pragma unroll
            for (int mi = 0; mi < 4; ++mi) {
                int row = wr * 64 + mi * 16 + lr;
                int ss = (ks * 4 + lks) ^ (row & 7);
                af[mi] = *reinterpret_cast<const bf16x8*>(As + row * 64 + ss * 8);
            }
            #pragma unroll
            for (int ni = 0; ni < 4; ++ni) {
                int row = wc * 64 + ni * 16 + lr;
                int ss = (ks * 4 + lks) ^ (row & 7);
                bfr[ni] = *reinterpret_cast<const bf16x8*>(Bs + row * 64 + ss * 8);
            }
            #pragma unroll
            for (int mi = 0; mi < 4; ++mi)
                #pragma unroll
                for (int ni = 0; ni < 4; ++ni)
                    acc[mi][ni] = __builtin_amdgcn_mfma_f32_16x16x32_bf16(af[mi], bfr[ni], acc[mi][ni], 0, 0, 0);
        }
    }
}

// ---------------- kernel: qkv GEMM (MFMA), scatter to q/k/v (B,H,T,64) ----------------
__global__ __launch_bounds__(256) void gemm_qkv_mfma(const unsigned short* __restrict__ A,
                                                     const unsigned short* __restrict__ Bt,
                                                     unsigned short* __restrict__ qb,
                                                     unsigned short* __restrict__ kb,
                                                     unsigned short* __restrict__ vb) {
    __shared__ unsigned short As[128 * 64];
    __shared__ unsigned short Bs[128 * 64];
    const int n0 = blockIdx.x * 128;
    const int m0 = blockIdx.y * 128;
    const int wid = threadIdx.x >> 6, lane = threadIdx.x & 63;
    const int wr = wid >> 1, wc = wid & 1;
    f32x4 acc[4][4] = {};
    gemm_mainloop(A, Bt, m0, n0, As, Bs, acc);
    #pragma unroll
    for (int mi = 0; mi < 4; ++mi)
    #pragma unroll
    for (int ni = 0; ni < 4; ++ni) {
        int col = n0 + wc * 64 + ni * 16 + (lane & 15);
        int which = col >> 10, rem = col & 1023;
        int hd = rem >> 6, ei = rem & 63;
        unsigned short* dst = which == 0 ? qb : (which == 1 ? kb : vb);
        #pragma unroll
        for (int r = 0; r < 4; ++r) {
            int row = m0 + wr * 64 + mi * 16 + (lane >> 4) * 4 + r;
            int bb = row >> 10, t = row & 1023;
            dst[(((size_t)(bb * 16 + hd) * 1024 + t) << 6) | ei] = f2bf(acc[mi][ni][r]);
        }
    }
}

// ---------------- kernel: out GEMM (MFMA), fused gate, f32 output ----------------
__global__ __launch_bounds__(256) void gemm_out_mfma(const unsigned short* __restrict__ A,
                                                     const unsigned short* __restrict__ Bt,
                                                     const float* __restrict__ mod,
                                                     float* __restrict__ out) {
    __shared__ unsigned short As[128 * 64];
    __shared__ unsigned short Bs[128 * 64];
    const int n0 = blockIdx.x * 128;
    const int m0 = blockIdx.y * 128;
    const int wid = threadIdx.x >> 6, lane = threadIdx.x & 63;
    const int wr = wid >> 1, wc = wid & 1;
    f32x4 acc[4][4] = {};
    gemm_mainloop(A, Bt, m0, n0, As, Bs, acc);
    #pragma unroll
    for (int mi = 0; mi < 4; ++mi)
    #pragma unroll
    for (int ni = 0; ni < 4; ++ni) {
        int col = n0 + wc * 64 + ni * 16 + (lane & 15);
        #pragma unroll
        for (int r = 0; r < 4; ++r) {
            int row = m0 + wr * 64 + mi * 16 + (lane >> 4) * 4 + r;
            int bb = row >> 10;
            float g = mod[bb * 3072 + 2048 + col];
            out[(size_t)row * 1024 + col] = acc[mi][ni][r] * g;
        }
    }
}

// ---------------- kernel: per-row (e=64) LN + RoPE on q,k; q pre-scaled by 1/8 ----------------
__global__ __launch_bounds__(256) void lnrope_kernel(unsigned short* __restrict__ qb,
                                                     unsigned short* __restrict__ kb,
                                                     const float* __restrict__ qw,
                                                     const float* __restrict__ kw,
                                                     const float* __restrict__ pos) {
    int gw = blockIdx.x * 4 + (threadIdx.x >> 6);
    int lane = threadIdx.x & 63;
    int half = gw >> 17;                            // 0 = q, 1 = k
    int row = gw & 131071;                          // (b*16+h)*1024 + t
    unsigned short* buf = half ? kb : qb;
    const float* w = half ? kw : qw;
    int t = row & 1023;
    size_t idx = (size_t)row * 64 + lane;
    float xv = bf2f(buf[idx]);
    float mean = wave_sum(xv) * (1.0f / 64.0f);
    float d = xv - mean;
    float var = wave_sum(d * d) * (1.0f / 64.0f);
    float y = d * rsqrtf(var + LN_EPS) * w[lane];
    float pv = (lane < 32) ? pos[t * 32 + lane] : 0.0f;
    float po = __shfl_xor(pv, 1);
    float py = __shfl_xor(y, 1);
    float res = y;
    if (lane < 32)
        res = ((lane & 1) == 0) ? (y * pv - py * po)
                                : (y * po + py * pv);
    buf[idx] = f2bf(half ? res : res * 0.125f);     // fold 1/sqrt(64) into q
}

// ---------------- kernel: MFMA flash attention ----------------
// grid 2048 = 128 bh * 16 qblocks; 4 waves; wave owns 16 q rows; KV chunks of 64.
__global__ __launch_bounds__(256) void attn_mfma_kernel(const unsigned short* __restrict__ qb,
                                                        const unsigned short* __restrict__ kb,
                                                        const unsigned short* __restrict__ vb,
                                                        unsigned short* __restrict__ ob) {
    __shared__ __align__(16) unsigned char smem[24576];
    unsigned short* Ks  = (unsigned short*)smem;            // [64 kv][64 d] swizzled
    unsigned short* Vt  = (unsigned short*)(smem + 8192);   // [64 d][64 kv] swizzled
    unsigned short* paQ = (unsigned short*)(smem + 16384);  // Qs at init, then pa[4][16*64]

    const int bid = blockIdx.x;
    const int swz = (bid & 7) * 256 + (bid >> 3);           // XCD-chunked
    const int bh = swz >> 4;
    const int q0 = (swz & 15) * 64;
    const int b = bh >> 4, hd = bh & 15;
    const size_t base = (size_t)bh << 16;                   // bh * 1024 * 64
    const int tid = threadIdx.x, wid = tid >> 6, lane = tid & 63;
    const int lr = lane & 15, g = lane >> 4;

    // ---- stage Q block (swizzled), load A-fragments to registers ----
    #pragma unroll
    for (int p = 0; p < 2; ++p) {
        int r = (tid >> 3) + p * 32;
        int sseg = tid & 7;
        int4 qv = *reinterpret_cast<const int4*>(qb + base + (size_t)(q0 + r) * 64 + sseg * 8);
        *reinterpret_cast<int4*>(paQ + r * 64 + ((sseg ^ (r & 7)) * 8)) = qv;
    }
    __syncthreads();
    bf16x8 af[2];
    #pragma unroll
    for (int ks = 0; ks < 2; ++ks) {
        int row = wid * 16 + lr;
        af[ks] = *reinterpret_cast<const bf16x8*>(paQ + row * 64 + (((ks * 4 + g) ^ (row & 7)) * 8));
    }

    f32x4 acc[4] = {};                 // O accum: nt = d-tile; rows q=(g*4+r), col d=nt*16+lr
    float m_run[4] = {-1e30f, -1e30f, -1e30f, -1e30f};
    float l_run[4] = {0.f, 0.f, 0.f, 0.f};
    unsigned short* pa_w = paQ + wid * 1024;   // wave-private P buffer [16 q][64 kv] swizzled

    for (int cc = 0; cc < 16; ++cc) {
        const int kv0 = cc * 64;
        __syncthreads();   // everyone done reading Ks/Vt (and chunk-0: Qs reads done)
        // ---- stage K chunk [64 kv][64 d] ----
        #pragma unroll
        for (int p = 0; p < 2; ++p) {
            int r = (tid >> 3) + p * 32;
            int sseg = tid & 7;
            int4 kv = *reinterpret_cast<const int4*>(kb + base + (size_t)(kv0 + r) * 64 + sseg * 8);
            *reinterpret_cast<int4*>(Ks + r * 64 + ((sseg ^ (r & 7)) * 8)) = kv;
        }
        // ---- stage V^T chunk [64 d][64 kv] via 8-gather ----
        #pragma unroll
        for (int p = 0; p < 2; ++p) {
            int idx = tid + p * 256;
            int d = idx >> 3;
            int kseg = idx & 7;
            unsigned short tmp[8];
            #pragma unroll
            for (int j = 0; j < 8; ++j)
                tmp[j] = vb[base + (size_t)(kv0 + kseg * 8 + j) * 64 + d];
            *reinterpret_cast<int4*>(Vt + d * 64 + ((kseg ^ (d & 7)) * 8)) =
                *reinterpret_cast<const int4*>(tmp);
        }
        __syncthreads();
        // ---- QK^T: S[16 q][64 kv] per wave (8 MFMAs) ----
        f32x4 s[4] = {};
        #pragma unroll
        for (int ks = 0; ks < 2; ++ks) {
            bf16x8 kf[4];
            #pragma unroll
            for (int nt = 0; nt < 4; ++nt) {
                int row = nt * 16 + lr;
                kf[nt] = *reinterpret_cast<const bf16x8*>(Ks + row * 64 + (((ks * 4 + g) ^ (row & 7)) * 8));
            }
            #pragma unroll
            for (int nt = 0; nt < 4; ++nt)
                s[nt] = __builtin_amdgcn_mfma_f32_16x16x32_bf16(af[ks], kf[nt], s[nt], 0, 0, 0);
        }
        // ---- online softmax (register-resident; rows q=g*4+r live in 16-lane groups) ----
        #pragma unroll
        for (int r = 0; r < 4; ++r) {
            float mx = fmaxf(fmaxf(s[0][r], s[1][r]), fmaxf(s[2][r], s[3][r]));
            #pragma unroll
            for (int o = 1; o <= 8; o <<= 1) mx = fmaxf(mx, __shfl_xor(mx, o));
            float mn = fmaxf(m_run[r], mx);
            float corr = __expf(m_run[r] - mn);
            m_run[r] = mn;
            float sum = 0.f;
            #pragma unroll
            for (int nt = 0; nt < 4; ++nt) {
                float e = __expf(s[nt][r] - mn);
                s[nt][r] = e;
                sum += e;
            }
            #pragma unroll
            for (int o = 1; o <= 8; o <<= 1) sum += __shfl_xor(sum, o);
            l_run[r] = l_run[r] * corr + sum;
            #pragma unroll
            for (int nt = 0; nt < 4; ++nt) acc[nt][r] *= corr;
        }
        // ---- write P (bf16) to wave-private LDS in A-fragment layout ----
        #pragma unroll
        for (int nt = 0; nt < 4; ++nt)
        #pragma unroll
        for (int r = 0; r < 4; ++r) {
            int q = g * 4 + r;
            pa_w[q * 64 + (((nt * 2 + (lr >> 3)) ^ (q & 7)) * 8) + (lr & 7)] = f2bf(s[nt][r]);
        }
        // ---- PV: O += P @ V (8 MFMAs) ----
        #pragma unroll
        for (int ks = 0; ks < 2; ++ks) {
            bf16x8 paf = *reinterpret_cast<const bf16x8*>(pa_w + lr * 64 + (((ks * 4 + g) ^ (lr & 7)) * 8));
            bf16x8 vf[4];
            #pragma unroll
            for (int nt = 0; nt < 4; ++nt) {
                int row = nt * 16 + lr;
                vf[nt] = *reinterpret_cast<const bf16x8*>(Vt + row * 64 + (((ks * 4 + g) ^ (row & 7)) * 8));
            }
            #pragma unroll
            for (int nt = 0; nt < 4; ++nt)
                acc[nt] = __builtin_amdgcn_mfma_f32_16x16x32_bf16(paf, vf[nt], acc[nt], 0, 0, 0);
        }
    }
    // ---- epilogue: O / l, write to (B, T, H*64) ----
    float inv[4];
    #pragma unroll
    for (int r = 0; r < 4; ++r) inv[r] = 1.0f / l_run[r];
    #pragma unroll
    for (int nt = 0; nt < 4; ++nt)
    #pragma unroll
    for (int r = 0; r < 4; ++r) {
        int q = q0 + wid * 16 + g * 4 + r;
        int d = hd * 64 + nt * 16 + lr;
        ob[(size_t)(b * 1024 + q) * 1024 + d] = f2bf(acc[nt][r] * inv[r]);
    }
}

extern "C" void kernel_launch(void* const* d_in, const int* in_sizes, int n_in,
                              void* d_out, int out_size, void* d_ws, size_t ws_size,
                              hipStream_t stream) {
    const float* x      = (const float*)d_in[0];
    const float* timep  = (const float*)d_in[1];
    const float* pos    = (const float*)d_in[2];
    const float* mod_w  = (const float*)d_in[3];
    const float* mod_b  = (const float*)d_in[4];
    const float* w_qkv  = (const float*)d_in[5];
    const float* w_out  = (const float*)d_in[6];
    const float* qw     = (const float*)d_in[7];
    const float* kw     = (const float*)d_in[8];
    float* outp = (float*)d_out;                   // f32 (8,1024,1024)

    char* ws = (char*)d_ws;
    float*          modbuf = (float*)ws;                          // 98304 B
    unsigned short* wqkvT  = (unsigned short*)(ws + 98304);       // bf16 [3072][1024]
    unsigned short* woutT  = (unsigned short*)(ws + 6389760);     // bf16 [1024][1024]
    unsigned short* hbuf   = (unsigned short*)(ws + 8486912);     // 16 MB (h, then o)
    unsigned short* qbuf   = hbuf + 8388608;
    unsigned short* kbuf   = qbuf + 8388608;
    unsigned short* vbuf   = kbuf + 8388608;
    unsigned short* obuf   = hbuf;

    transpose_cvt_kernel<<<dim3(96, 32), 256, 0, stream>>>(w_qkv, wqkvT, 1024, 3072);
    transpose_cvt_kernel<<<dim3(32, 32), 256, 0, stream>>>(w_out, woutT, 1024, 1024);
    mod_kernel<<<96, 256, 0, stream>>>(timep, mod_w, mod_b, modbuf);
    ln_mod_kernel<<<8192, 256, 0, stream>>>(x, modbuf, hbuf);
    gemm_qkv_mfma<<<dim3(24, 64), 256, 0, stream>>>(hbuf, wqkvT, qbuf, kbuf, vbuf);
    lnrope_kernel<<<65536, 256, 0, stream>>>(qbuf, kbuf, qw, kw, pos);
    attn_mfma_kernel<<<2048, 256, 0, stream>>>(qbuf, kbuf, vbuf, obuf);
    gemm_out_mfma<<<dim3(8, 64), 256, 0, stream>>>(obuf, woutT, modbuf, outp);
}

// Round 8
// 526.418 us; speedup vs baseline: 4.6023x; 1.0241x over previous
//
#include <hip/hip_runtime.h>

typedef short bf16x8 __attribute__((ext_vector_type(8)));
typedef float f32x4 __attribute__((ext_vector_type(4)));

#define LN_EPS 1e-6f

static __device__ __forceinline__ float bf2f(unsigned short u) {
    union { unsigned int i; float f; } v; v.i = ((unsigned int)u) << 16; return v.f;
}
static __device__ __forceinline__ unsigned short f2bf(float f) {
    union { float ff; unsigned int i; } v; v.ff = f;
    return (unsigned short)((v.i + 0x7FFFu + ((v.i >> 16) & 1u)) >> 16);  // RNE
}
static __device__ __forceinline__ float wave_sum(float v) {
    #pragma unroll
    for (int o = 32; o >= 1; o >>= 1) v += __shfl_xor(v, o);
    return v;
}

// ---------------- kernel: mod = silu(time) @ mod_w + mod_b  (8 x 3072) ----------------
__global__ __launch_bounds__(256) void mod_kernel(const float* __restrict__ timep,
                                                  const float* __restrict__ mod_w,
                                                  const float* __restrict__ mod_b,
                                                  float* __restrict__ mod) {
    __shared__ float st[1024];
    int b = blockIdx.x / 12;
    int j = (blockIdx.x % 12) * 256 + threadIdx.x;
    for (int i = threadIdx.x; i < 1024; i += 256) {
        float t = timep[b * 1024 + i];
        st[i] = t / (1.0f + __expf(-t));   // silu
    }
    __syncthreads();
    float acc = mod_b[j];
    for (int i = 0; i < 1024; ++i) acc = fmaf(st[i], mod_w[(size_t)i * 3072 + j], acc);
    mod[b * 3072 + j] = acc;
}

// ---------------- kernel: h = LN(x) * (scale+1) + shift  -> bf16 ----------------
__global__ __launch_bounds__(256) void ln_mod_kernel(const float* __restrict__ x,
                                                     const float* __restrict__ mod,
                                                     unsigned short* __restrict__ h) {
    __shared__ float red[8];
    int row = blockIdx.x;              // b*1024 + t
    int b = row >> 10;
    const float4 v = reinterpret_cast<const float4*>(x + (size_t)row * 1024)[threadIdx.x];
    float s  = v.x + v.y + v.z + v.w;
    float ss = v.x * v.x + v.y * v.y + v.z * v.z + v.w * v.w;
    #pragma unroll
    for (int o = 32; o >= 1; o >>= 1) { s += __shfl_xor(s, o); ss += __shfl_xor(ss, o); }
    int wid = threadIdx.x >> 6, lane = threadIdx.x & 63;
    if (lane == 0) { red[wid] = s; red[4 + wid] = ss; }
    __syncthreads();
    float mean = (red[0] + red[1] + red[2] + red[3]) * (1.0f / 1024.0f);
    float var  = (red[4] + red[5] + red[6] + red[7]) * (1.0f / 1024.0f) - mean * mean;
    float rstd = rsqrtf(var + LN_EPS);
    int d = threadIdx.x * 4;
    const float* mb = mod + b * 3072;
    float4 shf = *reinterpret_cast<const float4*>(mb + d);          // shift
    float4 scl = *reinterpret_cast<const float4*>(mb + 1024 + d);   // scale
    ushort4 o;
    o.x = f2bf((v.x - mean) * rstd * (scl.x + 1.0f) + shf.x);
    o.y = f2bf((v.y - mean) * rstd * (scl.y + 1.0f) + shf.y);
    o.z = f2bf((v.z - mean) * rstd * (scl.z + 1.0f) + shf.z);
    o.w = f2bf((v.w - mean) * rstd * (scl.w + 1.0f) + shf.w);
    reinterpret_cast<ushort4*>(h + (size_t)row * 1024)[threadIdx.x] = o;
}

// ---------------- kernel: fp32 [R][C] -> bf16 transposed [C][R] ----------------
__global__ __launch_bounds__(256) void transpose_cvt_kernel(const float* __restrict__ src,
                                                            unsigned short* __restrict__ dst,
                                                            int R, int C) {
    __shared__ unsigned short t[32][33];
    int c0 = blockIdx.x * 32, r0 = blockIdx.y * 32;
    int tx = threadIdx.x & 31, ty = threadIdx.x >> 5;
    #pragma unroll
    for (int i = 0; i < 4; ++i) {
        int r = ty + i * 8;
        t[r][tx] = f2bf(src[(size_t)(r0 + r) * C + c0 + tx]);
    }
    __syncthreads();
    #pragma unroll
    for (int i = 0; i < 4; ++i) {
        int c = ty + i * 8;
        dst[(size_t)(c0 + c) * R + r0 + tx] = t[tx][c];
    }
}

// ---------------- MFMA GEMM main loop: C[128x128] tile = A[128xK] @ Bt[128xK]^T ----------------
static __device__ __forceinline__ void gemm_mainloop(const unsigned short* __restrict__ A,
                                                     const unsigned short* __restrict__ Bt,
                                                     int m0, int n0,
                                                     unsigned short* As, unsigned short* Bs,
                                                     f32x4 (&acc)[4][4]) {
    const int tid = threadIdx.x;
    const int wid = tid >> 6, lane = tid & 63;
    const int wr = wid >> 1, wc = wid & 1;
    const int lr = lane & 15, lks = lane >> 4;
    const int srow = tid >> 3;
    const int sseg = tid & 7;
    int4 av[4], bv[4];
    #pragma unroll
    for (int i = 0; i < 4; ++i) {
        int r = i * 32 + srow;
        av[i] = *reinterpret_cast<const int4*>(A  + (size_t)(m0 + r) * 1024 + sseg * 8);
        bv[i] = *reinterpret_cast<const int4*>(Bt + (size_t)(n0 + r) * 1024 + sseg * 8);
    }
    for (int k0 = 0; k0 < 1024; k0 += 64) {
        __syncthreads();
        #pragma unroll
        for (int i = 0; i < 4; ++i) {
            int r = i * 32 + srow;
            int ss = sseg ^ (r & 7);
            *reinterpret_cast<int4*>(As + r * 64 + ss * 8) = av[i];
            *reinterpret_cast<int4*>(Bs + r * 64 + ss * 8) = bv[i];
        }
        __syncthreads();
        if (k0 + 64 < 1024) {
            #pragma unroll
            for (int i = 0; i < 4; ++i) {
                int r = i * 32 + srow;
                av[i] = *reinterpret_cast<const int4*>(A  + (size_t)(m0 + r) * 1024 + k0 + 64 + sseg * 8);
                bv[i] = *reinterpret_cast<const int4*>(Bt + (size_t)(n0 + r) * 1024 + k0 + 64 + sseg * 8);
            }
        }
        #pragma unroll
        for (int ks = 0; ks < 2; ++ks) {
            bf16x8 af[4], bfr[4];
            #pragma unroll
            for (int mi = 0; mi < 4; ++mi) {
                int row = wr * 64 + mi * 16 + lr;
                int ss = (ks * 4 + lks) ^ (row & 7);
                af[mi] = *reinterpret_cast<const bf16x8*>(As + row * 64 + ss * 8);
            }
            #pragma unroll
            for (int ni = 0; ni < 4; ++ni) {
                int row = wc * 64 + ni * 16 + lr;
                int ss = (ks * 4 + lks) ^ (row & 7);
                bfr[ni] = *reinterpret_cast<const bf16x8*>(Bs + row * 64 + ss * 8);
            }
            #pragma unroll
            for (int mi = 0; mi < 4; ++mi)
                #pragma unroll
                for (int ni = 0; ni < 4; ++ni)
                    acc[mi][ni] = __builtin_amdgcn_mfma_f32_16x16x32_bf16(af[mi], bfr[ni], acc[mi][ni], 0, 0, 0);
        }
    }
}

// ---------------- kernel: qkv GEMM (MFMA), LDS-bounce epilogue, scatter to q/k/v ----------------
__global__ __launch_bounds__(256) void gemm_qkv_mfma(const unsigned short* __restrict__ A,
                                                     const unsigned short* __restrict__ Bt,
                                                     unsigned short* __restrict__ qb,
                                                     unsigned short* __restrict__ kb,
                                                     unsigned short* __restrict__ vb) {
    __shared__ __align__(16) unsigned short smem[16384];   // As|Bs, then C bounce (32 KB)
    unsigned short* As = smem;
    unsigned short* Bs = smem + 8192;
    // XCD-aware swizzle: each XCD owns an 8-panel m-range (A L2-resident per XCD)
    const int bid = blockIdx.y * 24 + blockIdx.x;          // 0..1535
    const int xcd = bid & 7, idx = bid >> 3;               // idx 0..191
    const int m0 = (xcd * 8 + (idx & 7)) * 128;            // 0..8064
    const int n0 = (idx >> 3) * 128;                       // 0..2944
    const int tid = threadIdx.x;
    const int wid = tid >> 6, lane = tid & 63;
    const int wr = wid >> 1, wc = wid & 1;
    const int lr = lane & 15, g = lane >> 4;
    f32x4 acc[4][4] = {};
    gemm_mainloop(A, Bt, m0, n0, As, Bs, acc);
    // ---- bounce C tile through LDS; store full 128B lines ----
    __syncthreads();
    #pragma unroll
    for (int mi = 0; mi < 4; ++mi)
    #pragma unroll
    for (int ni = 0; ni < 4; ++ni)
    #pragma unroll
    for (int r = 0; r < 4; ++r) {
        int row = wr * 64 + mi * 16 + g * 4 + r;
        int col = wc * 64 + ni * 16 + lr;
        smem[row * 128 + col] = f2bf(acc[mi][ni][r]);
    }
    __syncthreads();
    #pragma unroll
    for (int p = 0; p < 8; ++p) {
        int seg = (tid >> 3) + p * 32;          // 0..255
        int row = seg >> 1, half = seg & 1, sub = tid & 7;
        int4 v = *reinterpret_cast<const int4*>(smem + row * 128 + half * 64 + sub * 8);
        int colb = n0 + half * 64;
        int which = colb >> 10, hd = (colb & 1023) >> 6;
        unsigned short* dst = which == 0 ? qb : (which == 1 ? kb : vb);
        int grow = m0 + row;
        int bb = grow >> 10, t = grow & 1023;
        *reinterpret_cast<int4*>(dst + (((size_t)(bb * 16 + hd) * 1024 + t) << 6) + sub * 8) = v;
    }
}

// ---------------- kernel: out GEMM (MFMA), 2-pass f32 LDS-bounce, fused gate ----------------
__global__ __launch_bounds__(256) void gemm_out_mfma(const unsigned short* __restrict__ A,
                                                     const unsigned short* __restrict__ Bt,
                                                     const float* __restrict__ mod,
                                                     float* __restrict__ out) {
    __shared__ __align__(16) unsigned short smem[16384];   // As|Bs, then f32 half-tile bounce
    unsigned short* As = smem;
    unsigned short* Bs = smem + 8192;
    float* fsm = reinterpret_cast<float*>(smem);           // [64][128] f32 = 32 KB
    const int bid = blockIdx.y * 8 + blockIdx.x;           // 0..511
    const int xcd = bid & 7, idx = bid >> 3;               // idx 0..63
    const int m0 = (xcd * 8 + (idx & 7)) * 128;
    const int n0 = (idx >> 3) * 128;                       // 0..896
    const int tid = threadIdx.x;
    const int wid = tid >> 6, lane = tid & 63;
    const int wr = wid >> 1, wc = wid & 1;
    const int lr = lane & 15, g = lane >> 4;
    f32x4 acc[4][4] = {};
    gemm_mainloop(A, Bt, m0, n0, As, Bs, acc);
    #pragma unroll
    for (int hp = 0; hp < 2; ++hp) {
        __syncthreads();
        if (wr == hp) {
            #pragma unroll
            for (int mi = 0; mi < 4; ++mi)
            #pragma unroll
            for (int ni = 0; ni < 4; ++ni)
            #pragma unroll
            for (int r = 0; r < 4; ++r)
                fsm[(mi * 16 + g * 4 + r) * 128 + wc * 64 + ni * 16 + lr] = acc[mi][ni][r];
        }
        __syncthreads();
        #pragma unroll
        for (int p = 0; p < 8; ++p) {
            int unit = tid + p * 256;           // 0..2047
            int lrow = unit >> 5, sub = unit & 31;
            float4 v = *reinterpret_cast<const float4*>(fsm + lrow * 128 + sub * 4);
            int row = m0 + hp * 64 + lrow;
            int col = n0 + sub * 4;
            int bb = row >> 10;
            float4 gv = *reinterpret_cast<const float4*>(mod + bb * 3072 + 2048 + col);
            float4 o4;
            o4.x = v.x * gv.x; o4.y = v.y * gv.y; o4.z = v.z * gv.z; o4.w = v.w * gv.w;
            *reinterpret_cast<float4*>(out + (size_t)row * 1024 + col) = o4;
        }
    }
}

// ---------------- kernel: per-row (e=64) LN + RoPE on q,k; q pre-scaled by 1/8 ----------------
__global__ __launch_bounds__(256) void lnrope_kernel(unsigned short* __restrict__ qb,
                                                     unsigned short* __restrict__ kb,
                                                     const float* __restrict__ qw,
                                                     const float* __restrict__ kw,
                                                     const float* __restrict__ pos) {
    int gw = blockIdx.x * 4 + (threadIdx.x >> 6);
    int lane = threadIdx.x & 63;
    int half = gw >> 17;                            // 0 = q, 1 = k
    int row = gw & 131071;                          // (b*16+h)*1024 + t
    unsigned short* buf = half ? kb : qb;
    const float* w = half ? kw : qw;
    int t = row & 1023;
    size_t idx = (size_t)row * 64 + lane;
    float xv = bf2f(buf[idx]);
    float mean = wave_sum(xv) * (1.0f / 64.0f);
    float d = xv - mean;
    float var = wave_sum(d * d) * (1.0f / 64.0f);
    float y = d * rsqrtf(var + LN_EPS) * w[lane];
    float pv = (lane < 32) ? pos[t * 32 + lane] : 0.0f;
    float po = __shfl_xor(pv, 1);
    float py = __shfl_xor(y, 1);
    float res = y;
    if (lane < 32)
        res = ((lane & 1) == 0) ? (y * pv - py * po)
                                : (y * po + py * pv);
    buf[idx] = f2bf(half ? res : res * 0.125f);     // fold 1/sqrt(64) into q
}

// ---------------- kernel: MFMA flash attention ----------------
__global__ __launch_bounds__(256) void attn_mfma_kernel(const unsigned short* __restrict__ qb,
                                                        const unsigned short* __restrict__ kb,
                                                        const unsigned short* __restrict__ vb,
                                                        unsigned short* __restrict__ ob) {
    __shared__ __align__(16) unsigned char smem[24576];
    unsigned short* Ks  = (unsigned short*)smem;            // [64 kv][64 d] swizzled
    unsigned short* Vt  = (unsigned short*)(smem + 8192);   // [64 d][64 kv] swizzled
    unsigned short* paQ = (unsigned short*)(smem + 16384);  // Qs at init, then pa[4][16*64]

    const int bid = blockIdx.x;
    const int swz = (bid & 7) * 256 + (bid >> 3);           // XCD-chunked
    const int bh = swz >> 4;
    const int q0 = (swz & 15) * 64;
    const int b = bh >> 4, hd = bh & 15;
    const size_t base = (size_t)bh << 16;                   // bh * 1024 * 64
    const int tid = threadIdx.x, wid = tid >> 6, lane = tid & 63;
    const int lr = lane & 15, g = lane >> 4;

    #pragma unroll
    for (int p = 0; p < 2; ++p) {
        int r = (tid >> 3) + p * 32;
        int sseg = tid & 7;
        int4 qv = *reinterpret_cast<const int4*>(qb + base + (size_t)(q0 + r) * 64 + sseg * 8);
        *reinterpret_cast<int4*>(paQ + r * 64 + ((sseg ^ (r & 7)) * 8)) = qv;
    }
    __syncthreads();
    bf16x8 af[2];
    #pragma unroll
    for (int ks = 0; ks < 2; ++ks) {
        int row = wid * 16 + lr;
        af[ks] = *reinterpret_cast<const bf16x8*>(paQ + row * 64 + (((ks * 4 + g) ^ (row & 7)) * 8));
    }

    f32x4 acc[4] = {};
    float m_run[4] = {-1e30f, -1e30f, -1e30f, -1e30f};
    float l_run[4] = {0.f, 0.f, 0.f, 0.f};
    unsigned short* pa_w = paQ + wid * 1024;

    for (int cc = 0; cc < 16; ++cc) {
        const int kv0 = cc * 64;
        __syncthreads();
        #pragma unroll
        for (int p = 0; p < 2; ++p) {
            int r = (tid >> 3) + p * 32;
            int sseg = tid & 7;
            int4 kv = *reinterpret_cast<const int4*>(kb + base + (size_t)(kv0 + r) * 64 + sseg * 8);
            *reinterpret_cast<int4*>(Ks + r * 64 + ((sseg ^ (r & 7)) * 8)) = kv;
        }
        #pragma unroll
        for (int p = 0; p < 2; ++p) {
            int idx = tid + p * 256;
            int d = idx >> 3;
            int kseg = idx & 7;
            unsigned short tmp[8];
            #pragma unroll
            for (int j = 0; j < 8; ++j)
                tmp[j] = vb[base + (size_t)(kv0 + kseg * 8 + j) * 64 + d];
            *reinterpret_cast<int4*>(Vt + d * 64 + ((kseg ^ (d & 7)) * 8)) =
                *reinterpret_cast<const int4*>(tmp);
        }
        __syncthreads();
        f32x4 s[4] = {};
        #pragma unroll
        for (int ks = 0; ks < 2; ++ks) {
            bf16x8 kf[4];
            #pragma unroll
            for (int nt = 0; nt < 4; ++nt) {
                int row = nt * 16 + lr;
                kf[nt] = *reinterpret_cast<const bf16x8*>(Ks + row * 64 + (((ks * 4 + g) ^ (row & 7)) * 8));
            }
            #pragma unroll
            for (int nt = 0; nt < 4; ++nt)
                s[nt] = __builtin_amdgcn_mfma_f32_16x16x32_bf16(af[ks], kf[nt], s[nt], 0, 0, 0);
        }
        #pragma unroll
        for (int r = 0; r < 4; ++r) {
            float mx = fmaxf(fmaxf(s[0][r], s[1][r]), fmaxf(s[2][r], s[3][r]));
            #pragma unroll
            for (int o = 1; o <= 8; o <<= 1) mx = fmaxf(mx, __shfl_xor(mx, o));
            float mn = fmaxf(m_run[r], mx);
            float corr = __expf(m_run[r] - mn);
            m_run[r] = mn;
            float sum = 0.f;
            #pragma unroll
            for (int nt = 0; nt < 4; ++nt) {
                float e = __expf(s[nt][r] - mn);
                s[nt][r] = e;
                sum += e;
            }
            #pragma unroll
            for (int o = 1; o <= 8; o <<= 1) sum += __shfl_xor(sum, o);
            l_run[r] = l_run[r] * corr + sum;
            #pragma unroll
            for (int nt = 0; nt < 4; ++nt) acc[nt][r] *= corr;
        }
        #pragma unroll
        for (int nt = 0; nt < 4; ++nt)
        #pragma unroll
        for (int r = 0; r < 4; ++r) {
            int q = g * 4 + r;
            pa_w[q * 64 + (((nt * 2 + (lr >> 3)) ^ (q & 7)) * 8) + (lr & 7)] = f2bf(s[nt][r]);
        }
        #pragma unroll
        for (int ks = 0; ks < 2; ++ks) {
            bf16x8 paf = *reinterpret_cast<const bf16x8*>(pa_w + lr * 64 + (((ks * 4 + g) ^ (lr & 7)) * 8));
            bf16x8 vf[4];
            #pragma unroll
            for (int nt = 0; nt < 4; ++nt) {
                int row = nt * 16 + lr;
                vf[nt] = *reinterpret_cast<const bf16x8*>(Vt + row * 64 + (((ks * 4 + g) ^ (row & 7)) * 8));
            }
            #pragma unroll
            for (int nt = 0; nt < 4; ++nt)
                acc[nt] = __builtin_amdgcn_mfma_f32_16x16x32_bf16(paf, vf[nt], acc[nt], 0, 0, 0);
        }
    }
    float inv[4];
    #pragma unroll
    for (int r = 0; r < 4; ++r) inv[r] = 1.0f / l_run[r];
    #pragma unroll
    for (int nt = 0; nt < 4; ++nt)
    #pragma unroll
    for (int r = 0; r < 4; ++r) {
        int q = q0 + wid * 16 + g * 4 + r;
        int d = hd * 64 + nt * 16 + lr;
        ob[(size_t)(b * 1024 + q) * 1024 + d] = f2bf(acc[nt][r] * inv[r]);
    }
}

extern "C" void kernel_launch(void* const* d_in, const int* in_sizes, int n_in,
                              void* d_out, int out_size, void* d_ws, size_t ws_size,
                              hipStream_t stream) {
    const float* x      = (const float*)d_in[0];
    const float* timep  = (const float*)d_in[1];
    const float* pos    = (const float*)d_in[2];
    const float* mod_w  = (const float*)d_in[3];
    const float* mod_b  = (const float*)d_in[4];
    const float* w_qkv  = (const float*)d_in[5];
    const float* w_out  = (const float*)d_in[6];
    const float* qw     = (const float*)d_in[7];
    const float* kw     = (const float*)d_in[8];
    float* outp = (float*)d_out;                   // f32 (8,1024,1024)

    char* ws = (char*)d_ws;
    float*          modbuf = (float*)ws;                          // 98304 B
    unsigned short* wqkvT  = (unsigned short*)(ws + 98304);       // bf16 [3072][1024]
    unsigned short* woutT  = (unsigned short*)(ws + 6389760);     // bf16 [1024][1024]
    unsigned short* hbuf   = (unsigned short*)(ws + 8486912);     // 16 MB (h, then o)
    unsigned short* qbuf   = hbuf + 8388608;
    unsigned short* kbuf   = qbuf + 8388608;
    unsigned short* vbuf   = kbuf + 8388608;
    unsigned short* obuf   = hbuf;

    transpose_cvt_kernel<<<dim3(96, 32), 256, 0, stream>>>(w_qkv, wqkvT, 1024, 3072);
    transpose_cvt_kernel<<<dim3(32, 32), 256, 0, stream>>>(w_out, woutT, 1024, 1024);
    mod_kernel<<<96, 256, 0, stream>>>(timep, mod_w, mod_b, modbuf);
    ln_mod_kernel<<<8192, 256, 0, stream>>>(x, modbuf, hbuf);
    gemm_qkv_mfma<<<dim3(24, 64), 256, 0, stream>>>(hbuf, wqkvT, qbuf, kbuf, vbuf);
    lnrope_kernel<<<65536, 256, 0, stream>>>(qbuf, kbuf, qw, kw, pos);
    attn_mfma_kernel<<<2048, 256, 0, stream>>>(qbuf, kbuf, vbuf, obuf);
    gemm_out_mfma<<<dim3(8, 64), 256, 0, stream>>>(obuf, woutT, modbuf, outp);
}

// Round 9
// 316.628 us; speedup vs baseline: 7.6516x; 1.6626x over previous
//
#include <hip/hip_runtime.h>

typedef short bf16x8 __attribute__((ext_vector_type(8)));
typedef float f32x4 __attribute__((ext_vector_type(4)));

#define LN_EPS 1e-6f

static __device__ __forceinline__ float bf2f(unsigned short u) {
    union { unsigned int i; float f; } v; v.i = ((unsigned int)u) << 16; return v.f;
}
static __device__ __forceinline__ unsigned short f2bf(float f) {
    union { float ff; unsigned int i; } v; v.ff = f;
    return (unsigned short)((v.i + 0x7FFFu + ((v.i >> 16) & 1u)) >> 16);  // RNE
}
static __device__ __forceinline__ float wave_sum(float v) {
    #pragma unroll
    for (int o = 32; o >= 1; o >>= 1) v += __shfl_xor(v, o);
    return v;
}
// async global->LDS, 16B per lane; LDS dest is wave-uniform base + lane*16
static __device__ __forceinline__ void gl_lds16(const unsigned short* g, unsigned short* l) {
    __builtin_amdgcn_global_load_lds((__attribute__((address_space(1))) void*)g,
                                     (__attribute__((address_space(3))) void*)l,
                                     16, 0, 0);
}

// ---------------- kernel: mod = silu(time) @ mod_w + mod_b  (8 x 3072) ----------------
__global__ __launch_bounds__(256) void mod_kernel(const float* __restrict__ timep,
                                                  const float* __restrict__ mod_w,
                                                  const float* __restrict__ mod_b,
                                                  float* __restrict__ mod) {
    __shared__ float st[1024];
    int b = blockIdx.x / 12;
    int j = (blockIdx.x % 12) * 256 + threadIdx.x;
    for (int i = threadIdx.x; i < 1024; i += 256) {
        float t = timep[b * 1024 + i];
        st[i] = t / (1.0f + __expf(-t));   // silu
    }
    __syncthreads();
    float acc = mod_b[j];
    for (int i = 0; i < 1024; ++i) acc = fmaf(st[i], mod_w[(size_t)i * 3072 + j], acc);
    mod[b * 3072 + j] = acc;
}

// ---------------- kernel: h = LN(x) * (scale+1) + shift  -> bf16 ----------------
__global__ __launch_bounds__(256) void ln_mod_kernel(const float* __restrict__ x,
                                                     const float* __restrict__ mod,
                                                     unsigned short* __restrict__ h) {
    __shared__ float red[8];
    int row = blockIdx.x;              // b*1024 + t
    int b = row >> 10;
    const float4 v = reinterpret_cast<const float4*>(x + (size_t)row * 1024)[threadIdx.x];
    float s  = v.x + v.y + v.z + v.w;
    float ss = v.x * v.x + v.y * v.y + v.z * v.z + v.w * v.w;
    #pragma unroll
    for (int o = 32; o >= 1; o >>= 1) { s += __shfl_xor(s, o); ss += __shfl_xor(ss, o); }
    int wid = threadIdx.x >> 6, lane = threadIdx.x & 63;
    if (lane == 0) { red[wid] = s; red[4 + wid] = ss; }
    __syncthreads();
    float mean = (red[0] + red[1] + red[2] + red[3]) * (1.0f / 1024.0f);
    float var  = (red[4] + red[5] + red[6] + red[7]) * (1.0f / 1024.0f) - mean * mean;
    float rstd = rsqrtf(var + LN_EPS);
    int d = threadIdx.x * 4;
    const float* mb = mod + b * 3072;
    float4 shf = *reinterpret_cast<const float4*>(mb + d);          // shift
    float4 scl = *reinterpret_cast<const float4*>(mb + 1024 + d);   // scale
    ushort4 o;
    o.x = f2bf((v.x - mean) * rstd * (scl.x + 1.0f) + shf.x);
    o.y = f2bf((v.y - mean) * rstd * (scl.y + 1.0f) + shf.y);
    o.z = f2bf((v.z - mean) * rstd * (scl.z + 1.0f) + shf.z);
    o.w = f2bf((v.w - mean) * rstd * (scl.w + 1.0f) + shf.w);
    reinterpret_cast<ushort4*>(h + (size_t)row * 1024)[threadIdx.x] = o;
}

// ---------------- kernel: fp32 [R][C] -> bf16 transposed [C][R] ----------------
__global__ __launch_bounds__(256) void transpose_cvt_kernel(const float* __restrict__ src,
                                                            unsigned short* __restrict__ dst,
                                                            int R, int C) {
    __shared__ unsigned short t[32][33];
    int c0 = blockIdx.x * 32, r0 = blockIdx.y * 32;
    int tx = threadIdx.x & 31, ty = threadIdx.x >> 5;
    #pragma unroll
    for (int i = 0; i < 4; ++i) {
        int r = ty + i * 8;
        t[r][tx] = f2bf(src[(size_t)(r0 + r) * C + c0 + tx]);
    }
    __syncthreads();
    #pragma unroll
    for (int i = 0; i < 4; ++i) {
        int c = ty + i * 8;
        dst[(size_t)(c0 + c) * R + r0 + tx] = t[tx][c];
    }
}

// ---------------- MFMA GEMM main loop (m97 structure): global_load_lds staging ----------------
// LDS linear [128 rows][8 segs of 16B]; XOR swizzle applied on the GLOBAL source address:
// LDS[r][s] = X[r][k0 + (s ^ (r&7))*8]  -> conflict-free ds_read_b128 fragment reads.
static __device__ __forceinline__ void gemm_mainloop(const unsigned short* __restrict__ A,
                                                     const unsigned short* __restrict__ Bt,
                                                     int m0, int n0,
                                                     unsigned short* As, unsigned short* Bs,
                                                     f32x4 (&acc)[4][4]) {
    const int tid = threadIdx.x;
    const int wid = tid >> 6, lane = tid & 63;
    const int wr = wid >> 1, wc = wid & 1;
    const int lr = lane & 15, lks = lane >> 4;
    // per-lane pre-swizzled global offset: row = lane>>3, seg = (lane&7) ^ (lane>>3)
    const int gofs = (lane >> 3) * 1024 + (((lane & 7) ^ (lane >> 3)) * 8);
    const unsigned short* Ag = A  + (size_t)(m0 + wid * 32) * 1024 + gofs;
    const unsigned short* Bg = Bt + (size_t)(n0 + wid * 32) * 1024 + gofs;
    unsigned short* AsW = As + wid * 32 * 64;   // wave-uniform LDS bases
    unsigned short* BsW = Bs + wid * 32 * 64;
    for (int k0 = 0; k0 < 1024; k0 += 64) {
        __syncthreads();   // previous compute done reading LDS
        #pragma unroll
        for (int j = 0; j < 4; ++j) {           // 8 rows per issue, 32 rows per wave
            gl_lds16(Ag + k0 + j * 8192, AsW + j * 512);
            gl_lds16(Bg + k0 + j * 8192, BsW + j * 512);
        }
        __syncthreads();   // drains vmcnt -> staged tile visible
        #pragma unroll
        for (int ks = 0; ks < 2; ++ks) {
            bf16x8 af[4], bfr[4];
            #pragma unroll
            for (int mi = 0; mi < 4; ++mi) {
                int row = wr * 64 + mi * 16 + lr;
                int ss = (ks * 4 + lks) ^ (row & 7);
                af[mi] = *reinterpret_cast<const bf16x8*>(As + row * 64 + ss * 8);
            }
            #pragma unroll
            for (int ni = 0; ni < 4; ++ni) {
                int row = wc * 64 + ni * 16 + lr;
                int ss = (ks * 4 + lks) ^ (row & 7);
                bfr[ni] = *reinterpret_cast<const bf16x8*>(Bs + row * 64 + ss * 8);
            }
            #pragma unroll
            for (int mi = 0; mi < 4; ++mi)
                #pragma unroll
                for (int ni = 0; ni < 4; ++ni)
                    acc[mi][ni] = __builtin_amdgcn_mfma_f32_16x16x32_bf16(af[mi], bfr[ni], acc[mi][ni], 0, 0, 0);
        }
    }
}

// ---------------- kernel: qkv GEMM (MFMA), LDS-bounce epilogue, scatter to q/k/v ----------------
__global__ __launch_bounds__(256) void gemm_qkv_mfma(const unsigned short* __restrict__ A,
                                                     const unsigned short* __restrict__ Bt,
                                                     unsigned short* __restrict__ qb,
                                                     unsigned short* __restrict__ kb,
                                                     unsigned short* __restrict__ vb) {
    __shared__ __align__(16) unsigned short smem[16384];   // As|Bs, then C bounce (32 KB)
    unsigned short* As = smem;
    unsigned short* Bs = smem + 8192;
    const int bid = blockIdx.y * 24 + blockIdx.x;          // 0..1535
    const int xcd = bid & 7, idx = bid >> 3;               // idx 0..191
    const int m0 = (xcd * 8 + (idx & 7)) * 128;
    const int n0 = (idx >> 3) * 128;
    const int tid = threadIdx.x;
    const int wid = tid >> 6, lane = tid & 63;
    const int wr = wid >> 1, wc = wid & 1;
    const int lr = lane & 15, g = lane >> 4;
    f32x4 acc[4][4] = {};
    gemm_mainloop(A, Bt, m0, n0, As, Bs, acc);
    __syncthreads();
    #pragma unroll
    for (int mi = 0; mi < 4; ++mi)
    #pragma unroll
    for (int ni = 0; ni < 4; ++ni)
    #pragma unroll
    for (int r = 0; r < 4; ++r) {
        int row = wr * 64 + mi * 16 + g * 4 + r;
        int col = wc * 64 + ni * 16 + lr;
        smem[row * 128 + col] = f2bf(acc[mi][ni][r]);
    }
    __syncthreads();
    #pragma unroll
    for (int p = 0; p < 8; ++p) {
        int seg = (tid >> 3) + p * 32;          // 0..255
        int row = seg >> 1, half = seg & 1, sub = tid & 7;
        int4 v = *reinterpret_cast<const int4*>(smem + row * 128 + half * 64 + sub * 8);
        int colb = n0 + half * 64;
        int which = colb >> 10, hd = (colb & 1023) >> 6;
        unsigned short* dst = which == 0 ? qb : (which == 1 ? kb : vb);
        int grow = m0 + row;
        int bb = grow >> 10, t = grow & 1023;
        *reinterpret_cast<int4*>(dst + (((size_t)(bb * 16 + hd) * 1024 + t) << 6) + sub * 8) = v;
    }
}

// ---------------- kernel: out GEMM (MFMA), 2-pass f32 LDS-bounce, fused gate ----------------
__global__ __launch_bounds__(256) void gemm_out_mfma(const unsigned short* __restrict__ A,
                                                     const unsigned short* __restrict__ Bt,
                                                     const float* __restrict__ mod,
                                                     float* __restrict__ out) {
    __shared__ __align__(16) unsigned short smem[16384];
    unsigned short* As = smem;
    unsigned short* Bs = smem + 8192;
    float* fsm = reinterpret_cast<float*>(smem);           // [64][128] f32 = 32 KB
    const int bid = blockIdx.y * 8 + blockIdx.x;           // 0..511
    const int xcd = bid & 7, idx = bid >> 3;
    const int m0 = (xcd * 8 + (idx & 7)) * 128;
    const int n0 = (idx >> 3) * 128;
    const int tid = threadIdx.x;
    const int wid = tid >> 6, lane = tid & 63;
    const int wr = wid >> 1, wc = wid & 1;
    const int lr = lane & 15, g = lane >> 4;
    f32x4 acc[4][4] = {};
    gemm_mainloop(A, Bt, m0, n0, As, Bs, acc);
    #pragma unroll
    for (int hp = 0; hp < 2; ++hp) {
        __syncthreads();
        if (wr == hp) {
            #pragma unroll
            for (int mi = 0; mi < 4; ++mi)
            #pragma unroll
            for (int ni = 0; ni < 4; ++ni)
            #pragma unroll
            for (int r = 0; r < 4; ++r)
                fsm[(mi * 16 + g * 4 + r) * 128 + wc * 64 + ni * 16 + lr] = acc[mi][ni][r];
        }
        __syncthreads();
        #pragma unroll
        for (int p = 0; p < 8; ++p) {
            int unit = tid + p * 256;           // 0..2047
            int lrow = unit >> 5, sub = unit & 31;
            float4 v = *reinterpret_cast<const float4*>(fsm + lrow * 128 + sub * 4);
            int row = m0 + hp * 64 + lrow;
            int col = n0 + sub * 4;
            int bb = row >> 10;
            float4 gv = *reinterpret_cast<const float4*>(mod + bb * 3072 + 2048 + col);
            float4 o4;
            o4.x = v.x * gv.x; o4.y = v.y * gv.y; o4.z = v.z * gv.z; o4.w = v.w * gv.w;
            *reinterpret_cast<float4*>(out + (size_t)row * 1024 + col) = o4;
        }
    }
}

// ---------------- kernel: per-row (e=64) LN + RoPE on q,k; q pre-scaled by 1/8 ----------------
__global__ __launch_bounds__(256) void lnrope_kernel(unsigned short* __restrict__ qb,
                                                     unsigned short* __restrict__ kb,
                                                     const float* __restrict__ qw,
                                                     const float* __restrict__ kw,
                                                     const float* __restrict__ pos) {
    int gw = blockIdx.x * 4 + (threadIdx.x >> 6);
    int lane = threadIdx.x & 63;
    int half = gw >> 17;                            // 0 = q, 1 = k
    int row = gw & 131071;                          // (b*16+h)*1024 + t
    unsigned short* buf = half ? kb : qb;
    const float* w = half ? kw : qw;
    int t = row & 1023;
    size_t idx = (size_t)row * 64 + lane;
    float xv = bf2f(buf[idx]);
    float mean = wave_sum(xv) * (1.0f / 64.0f);
    float d = xv - mean;
    float var = wave_sum(d * d) * (1.0f / 64.0f);
    float y = d * rsqrtf(var + LN_EPS) * w[lane];
    float pv = (lane < 32) ? pos[t * 32 + lane] : 0.0f;
    float po = __shfl_xor(pv, 1);
    float py = __shfl_xor(y, 1);
    float res = y;
    if (lane < 32)
        res = ((lane & 1) == 0) ? (y * pv - py * po)
                                : (y * po + py * pv);
    buf[idx] = f2bf(half ? res : res * 0.125f);     // fold 1/sqrt(64) into q
}

// ---------------- kernel: MFMA flash attention ----------------
__global__ __launch_bounds__(256) void attn_mfma_kernel(const unsigned short* __restrict__ qb,
                                                        const unsigned short* __restrict__ kb,
                                                        const unsigned short* __restrict__ vb,
                                                        unsigned short* __restrict__ ob) {
    __shared__ __align__(16) unsigned char smem[24576];
    unsigned short* Ks  = (unsigned short*)smem;            // [64 kv][64 d] swizzled
    unsigned short* Vt  = (unsigned short*)(smem + 8192);   // [64 d][64 kv] swizzled
    unsigned short* paQ = (unsigned short*)(smem + 16384);  // Qs at init, then pa[4][16*64]

    const int bid = blockIdx.x;
    const int swz = (bid & 7) * 256 + (bid >> 3);           // XCD-chunked
    const int bh = swz >> 4;
    const int q0 = (swz & 15) * 64;
    const int b = bh >> 4, hd = bh & 15;
    const size_t base = (size_t)bh << 16;                   // bh * 1024 * 64
    const int tid = threadIdx.x, wid = tid >> 6, lane = tid & 63;
    const int lr = lane & 15, g = lane >> 4;

    #pragma unroll
    for (int p = 0; p < 2; ++p) {
        int r = (tid >> 3) + p * 32;
        int sseg = tid & 7;
        int4 qv = *reinterpret_cast<const int4*>(qb + base + (size_t)(q0 + r) * 64 + sseg * 8);
        *reinterpret_cast<int4*>(paQ + r * 64 + ((sseg ^ (r & 7)) * 8)) = qv;
    }
    __syncthreads();
    bf16x8 af[2];
    #pragma unroll
    for (int ks = 0; ks < 2; ++ks) {
        int row = wid * 16 + lr;
        af[ks] = *reinterpret_cast<const bf16x8*>(paQ + row * 64 + (((ks * 4 + g) ^ (row & 7)) * 8));
    }

    f32x4 acc[4] = {};
    float m_run[4] = {-1e30f, -1e30f, -1e30f, -1e30f};
    float l_run[4] = {0.f, 0.f, 0.f, 0.f};
    unsigned short* pa_w = paQ + wid * 1024;

    for (int cc = 0; cc < 16; ++cc) {
        const int kv0 = cc * 64;
        __syncthreads();
        #pragma unroll
        for (int p = 0; p < 2; ++p) {
            int r = (tid >> 3) + p * 32;
            int sseg = tid & 7;
            int4 kv = *reinterpret_cast<const int4*>(kb + base + (size_t)(kv0 + r) * 64 + sseg * 8);
            *reinterpret_cast<int4*>(Ks + r * 64 + ((sseg ^ (r & 7)) * 8)) = kv;
        }
        #pragma unroll
        for (int p = 0; p < 2; ++p) {
            int idx = tid + p * 256;
            int d = idx >> 3;
            int kseg = idx & 7;
            unsigned short tmp[8];
            #pragma unroll
            for (int j = 0; j < 8; ++j)
                tmp[j] = vb[base + (size_t)(kv0 + kseg * 8 + j) * 64 + d];
            *reinterpret_cast<int4*>(Vt + d * 64 + ((kseg ^ (d & 7)) * 8)) =
                *reinterpret_cast<const int4*>(tmp);
        }
        __syncthreads();
        f32x4 s[4] = {};
        #pragma unroll
        for (int ks = 0; ks < 2; ++ks) {
            bf16x8 kf[4];
            #pragma unroll
            for (int nt = 0; nt < 4; ++nt) {
                int row = nt * 16 + lr;
                kf[nt] = *reinterpret_cast<const bf16x8*>(Ks + row * 64 + (((ks * 4 + g) ^ (row & 7)) * 8));
            }
            #pragma unroll
            for (int nt = 0; nt < 4; ++nt)
                s[nt] = __builtin_amdgcn_mfma_f32_16x16x32_bf16(af[ks], kf[nt], s[nt], 0, 0, 0);
        }
        #pragma unroll
        for (int r = 0; r < 4; ++r) {
            float mx = fmaxf(fmaxf(s[0][r], s[1][r]), fmaxf(s[2][r], s[3][r]));
            #pragma unroll
            for (int o = 1; o <= 8; o <<= 1) mx = fmaxf(mx, __shfl_xor(mx, o));
            float mn = fmaxf(m_run[r], mx);
            float corr = __expf(m_run[r] - mn);
            m_run[r] = mn;
            float sum = 0.f;
            #pragma unroll
            for (int nt = 0; nt < 4; ++nt) {
                float e = __expf(s[nt][r] - mn);
                s[nt][r] = e;
                sum += e;
            }
            #pragma unroll
            for (int o = 1; o <= 8; o <<= 1) sum += __shfl_xor(sum, o);
            l_run[r] = l_run[r] * corr + sum;
            #pragma unroll
            for (int nt = 0; nt < 4; ++nt) acc[nt][r] *= corr;
        }
        #pragma unroll
        for (int nt = 0; nt < 4; ++nt)
        #pragma unroll
        for (int r = 0; r < 4; ++r) {
            int q = g * 4 + r;
            pa_w[q * 64 + (((nt * 2 + (lr >> 3)) ^ (q & 7)) * 8) + (lr & 7)] = f2bf(s[nt][r]);
        }
        #pragma unroll
        for (int ks = 0; ks < 2; ++ks) {
            bf16x8 paf = *reinterpret_cast<const bf16x8*>(pa_w + lr * 64 + (((ks * 4 + g) ^ (lr & 7)) * 8));
            bf16x8 vf[4];
            #pragma unroll
            for (int nt = 0; nt < 4; ++nt) {
                int row = nt * 16 + lr;
                vf[nt] = *reinterpret_cast<const bf16x8*>(Vt + row * 64 + (((ks * 4 + g) ^ (row & 7)) * 8));
            }
            #pragma unroll
            for (int nt = 0; nt < 4; ++nt)
                acc[nt] = __builtin_amdgcn_mfma_f32_16x16x32_bf16(paf, vf[nt], acc[nt], 0, 0, 0);
        }
    }
    float inv[4];
    #pragma unroll
    for (int r = 0; r < 4; ++r) inv[r] = 1.0f / l_run[r];
    #pragma unroll
    for (int nt = 0; nt < 4; ++nt)
    #pragma unroll
    for (int r = 0; r < 4; ++r) {
        int q = q0 + wid * 16 + g * 4 + r;
        int d = hd * 64 + nt * 16 + lr;
        ob[(size_t)(b * 1024 + q) * 1024 + d] = f2bf(acc[nt][r] * inv[r]);
    }
}

extern "C" void kernel_launch(void* const* d_in, const int* in_sizes, int n_in,
                              void* d_out, int out_size, void* d_ws, size_t ws_size,
                              hipStream_t stream) {
    const float* x      = (const float*)d_in[0];
    const float* timep  = (const float*)d_in[1];
    const float* pos    = (const float*)d_in[2];
    const float* mod_w  = (const float*)d_in[3];
    const float* mod_b  = (const float*)d_in[4];
    const float* w_qkv  = (const float*)d_in[5];
    const float* w_out  = (const float*)d_in[6];
    const float* qw     = (const float*)d_in[7];
    const float* kw     = (const float*)d_in[8];
    float* outp = (float*)d_out;                   // f32 (8,1024,1024)

    char* ws = (char*)d_ws;
    float*          modbuf = (float*)ws;                          // 98304 B
    unsigned short* wqkvT  = (unsigned short*)(ws + 98304);       // bf16 [3072][1024]
    unsigned short* woutT  = (unsigned short*)(ws + 6389760);     // bf16 [1024][1024]
    unsigned short* hbuf   = (unsigned short*)(ws + 8486912);     // 16 MB (h, then o)
    unsigned short* qbuf   = hbuf + 8388608;
    unsigned short* kbuf   = qbuf + 8388608;
    unsigned short* vbuf   = kbuf + 8388608;
    unsigned short* obuf   = hbuf;

    transpose_cvt_kernel<<<dim3(96, 32), 256, 0, stream>>>(w_qkv, wqkvT, 1024, 3072);
    transpose_cvt_kernel<<<dim3(32, 32), 256, 0, stream>>>(w_out, woutT, 1024, 1024);
    mod_kernel<<<96, 256, 0, stream>>>(timep, mod_w, mod_b, modbuf);
    ln_mod_kernel<<<8192, 256, 0, stream>>>(x, modbuf, hbuf);
    gemm_qkv_mfma<<<dim3(24, 64), 256, 0, stream>>>(hbuf, wqkvT, qbuf, kbuf, vbuf);
    lnrope_kernel<<<65536, 256, 0, stream>>>(qbuf, kbuf, qw, kw, pos);
    attn_mfma_kernel<<<2048, 256, 0, stream>>>(qbuf, kbuf, vbuf, obuf);
    gemm_out_mfma<<<dim3(8, 64), 256, 0, stream>>>(obuf, woutT, modbuf, outp);
}

// Round 10
// 300.209 us; speedup vs baseline: 8.0701x; 1.0547x over previous
//
#include <hip/hip_runtime.h>

typedef short bf16x8 __attribute__((ext_vector_type(8)));
typedef float f32x4 __attribute__((ext_vector_type(4)));

#define LN_EPS 1e-6f

static __device__ __forceinline__ float bf2f(unsigned short u) {
    union { unsigned int i; float f; } v; v.i = ((unsigned int)u) << 16; return v.f;
}
static __device__ __forceinline__ unsigned short f2bf(float f) {
    union { float ff; unsigned int i; } v; v.ff = f;
    return (unsigned short)((v.i + 0x7FFFu + ((v.i >> 16) & 1u)) >> 16);  // RNE
}
static __device__ __forceinline__ float wave_sum(float v) {
    #pragma unroll
    for (int o = 32; o >= 1; o >>= 1) v += __shfl_xor(v, o);
    return v;
}
// async global->LDS, 16B per lane; LDS dest is wave-uniform base + lane*16
static __device__ __forceinline__ void gl_lds16(const unsigned short* g, unsigned short* l) {
    __builtin_amdgcn_global_load_lds((__attribute__((address_space(1))) void*)g,
                                     (__attribute__((address_space(3))) void*)l,
                                     16, 0, 0);
}

// ---------------- kernel: mod = silu(time) @ mod_w + mod_b  (8 x 3072) ----------------
__global__ __launch_bounds__(256) void mod_kernel(const float* __restrict__ timep,
                                                  const float* __restrict__ mod_w,
                                                  const float* __restrict__ mod_b,
                                                  float* __restrict__ mod) {
    __shared__ float st[1024];
    int b = blockIdx.x / 12;
    int j = (blockIdx.x % 12) * 256 + threadIdx.x;
    for (int i = threadIdx.x; i < 1024; i += 256) {
        float t = timep[b * 1024 + i];
        st[i] = t / (1.0f + __expf(-t));   // silu
    }
    __syncthreads();
    float acc = mod_b[j];
    for (int i = 0; i < 1024; ++i) acc = fmaf(st[i], mod_w[(size_t)i * 3072 + j], acc);
    mod[b * 3072 + j] = acc;
}

// ---------------- kernel: h = LN(x) * (scale+1) + shift  -> bf16 ----------------
__global__ __launch_bounds__(256) void ln_mod_kernel(const float* __restrict__ x,
                                                     const float* __restrict__ mod,
                                                     unsigned short* __restrict__ h) {
    __shared__ float red[8];
    int row = blockIdx.x;              // b*1024 + t
    int b = row >> 10;
    const float4 v = reinterpret_cast<const float4*>(x + (size_t)row * 1024)[threadIdx.x];
    float s  = v.x + v.y + v.z + v.w;
    float ss = v.x * v.x + v.y * v.y + v.z * v.z + v.w * v.w;
    #pragma unroll
    for (int o = 32; o >= 1; o >>= 1) { s += __shfl_xor(s, o); ss += __shfl_xor(ss, o); }
    int wid = threadIdx.x >> 6, lane = threadIdx.x & 63;
    if (lane == 0) { red[wid] = s; red[4 + wid] = ss; }
    __syncthreads();
    float mean = (red[0] + red[1] + red[2] + red[3]) * (1.0f / 1024.0f);
    float var  = (red[4] + red[5] + red[6] + red[7]) * (1.0f / 1024.0f) - mean * mean;
    float rstd = rsqrtf(var + LN_EPS);
    int d = threadIdx.x * 4;
    const float* mb = mod + b * 3072;
    float4 shf = *reinterpret_cast<const float4*>(mb + d);          // shift
    float4 scl = *reinterpret_cast<const float4*>(mb + 1024 + d);   // scale
    ushort4 o;
    o.x = f2bf((v.x - mean) * rstd * (scl.x + 1.0f) + shf.x);
    o.y = f2bf((v.y - mean) * rstd * (scl.y + 1.0f) + shf.y);
    o.z = f2bf((v.z - mean) * rstd * (scl.z + 1.0f) + shf.z);
    o.w = f2bf((v.w - mean) * rstd * (scl.w + 1.0f) + shf.w);
    reinterpret_cast<ushort4*>(h + (size_t)row * 1024)[threadIdx.x] = o;
}

// ---------------- kernel: fp32 [R][C] -> bf16 transposed [C][R] ----------------
__global__ __launch_bounds__(256) void transpose_cvt_kernel(const float* __restrict__ src,
                                                            unsigned short* __restrict__ dst,
                                                            int R, int C) {
    __shared__ unsigned short t[32][33];
    int c0 = blockIdx.x * 32, r0 = blockIdx.y * 32;
    int tx = threadIdx.x & 31, ty = threadIdx.x >> 5;
    #pragma unroll
    for (int i = 0; i < 4; ++i) {
        int r = ty + i * 8;
        t[r][tx] = f2bf(src[(size_t)(r0 + r) * C + c0 + tx]);
    }
    __syncthreads();
    #pragma unroll
    for (int i = 0; i < 4; ++i) {
        int c = ty + i * 8;
        dst[(size_t)(c0 + c) * R + r0 + tx] = t[tx][c];
    }
}

// ---------------- MFMA GEMM main loop (m97 structure): global_load_lds staging ----------------
static __device__ __forceinline__ void gemm_mainloop(const unsigned short* __restrict__ A,
                                                     const unsigned short* __restrict__ Bt,
                                                     int m0, int n0,
                                                     unsigned short* As, unsigned short* Bs,
                                                     f32x4 (&acc)[4][4]) {
    const int tid = threadIdx.x;
    const int wid = tid >> 6, lane = tid & 63;
    const int wr = wid >> 1, wc = wid & 1;
    const int lr = lane & 15, lks = lane >> 4;
    const int gofs = (lane >> 3) * 1024 + (((lane & 7) ^ (lane >> 3)) * 8);
    const unsigned short* Ag = A  + (size_t)(m0 + wid * 32) * 1024 + gofs;
    const unsigned short* Bg = Bt + (size_t)(n0 + wid * 32) * 1024 + gofs;
    unsigned short* AsW = As + wid * 32 * 64;
    unsigned short* BsW = Bs + wid * 32 * 64;
    for (int k0 = 0; k0 < 1024; k0 += 64) {
        __syncthreads();
        #pragma unroll
        for (int j = 0; j < 4; ++j) {
            gl_lds16(Ag + k0 + j * 8192, AsW + j * 512);
            gl_lds16(Bg + k0 + j * 8192, BsW + j * 512);
        }
        __syncthreads();
        #pragma unroll
        for (int ks = 0; ks < 2; ++ks) {
            bf16x8 af[4], bfr[4];
            #pragma unroll
            for (int mi = 0; mi < 4; ++mi) {
                int row = wr * 64 + mi * 16 + lr;
                int ss = (ks * 4 + lks) ^ (row & 7);
                af[mi] = *reinterpret_cast<const bf16x8*>(As + row * 64 + ss * 8);
            }
            #pragma unroll
            for (int ni = 0; ni < 4; ++ni) {
                int row = wc * 64 + ni * 16 + lr;
                int ss = (ks * 4 + lks) ^ (row & 7);
                bfr[ni] = *reinterpret_cast<const bf16x8*>(Bs + row * 64 + ss * 8);
            }
            #pragma unroll
            for (int mi = 0; mi < 4; ++mi)
                #pragma unroll
                for (int ni = 0; ni < 4; ++ni)
                    acc[mi][ni] = __builtin_amdgcn_mfma_f32_16x16x32_bf16(af[mi], bfr[ni], acc[mi][ni], 0, 0, 0);
        }
    }
}

// ---------------- kernel: qkv GEMM (MFMA); q/k scattered (B,H,T,64); v stored TRANSPOSED (B,H,64,T) ----------------
__global__ __launch_bounds__(256) void gemm_qkv_mfma(const unsigned short* __restrict__ A,
                                                     const unsigned short* __restrict__ Bt,
                                                     unsigned short* __restrict__ qb,
                                                     unsigned short* __restrict__ kb,
                                                     unsigned short* __restrict__ vb) {
    __shared__ __align__(16) unsigned short smem[16640];   // As|Bs (16384), bounce uses stride 130
    unsigned short* As = smem;
    unsigned short* Bs = smem + 8192;
    const int bid = blockIdx.y * 24 + blockIdx.x;
    const int xcd = bid & 7, idx = bid >> 3;
    const int m0 = (xcd * 8 + (idx & 7)) * 128;
    const int n0 = (idx >> 3) * 128;
    const int tid = threadIdx.x;
    const int wid = tid >> 6, lane = tid & 63;
    const int wr = wid >> 1, wc = wid & 1;
    const int lr = lane & 15, g = lane >> 4;
    const int which = n0 >> 10;                     // block-uniform: 0=q 1=k 2=v
    f32x4 acc[4][4] = {};
    gemm_mainloop(A, Bt, m0, n0, As, Bs, acc);
    __syncthreads();
    // ---- bounce C tile to LDS (stride 130); v blocks bounce TRANSPOSED ----
    #pragma unroll
    for (int mi = 0; mi < 4; ++mi)
    #pragma unroll
    for (int ni = 0; ni < 4; ++ni)
    #pragma unroll
    for (int r = 0; r < 4; ++r) {
        int row = wr * 64 + mi * 16 + g * 4 + r;
        int col = wc * 64 + ni * 16 + lr;
        if (which == 2) smem[col * 130 + row] = f2bf(acc[mi][ni][r]);
        else            smem[row * 130 + col] = f2bf(acc[mi][ni][r]);
    }
    __syncthreads();
    const int bb = m0 >> 10, tbase = m0 & 1023;
    if (which == 2) {
        // transposed store: 16B along t
        #pragma unroll
        for (int p = 0; p < 8; ++p) {
            int seg = (tid >> 3) + p * 32;          // 0..255
            int erow = seg >> 1, half = seg & 1, sub = tid & 7;
            int4 v = *reinterpret_cast<const int4*>(smem + erow * 130 + half * 64 + sub * 8);
            int eg = (n0 & 1023) + erow;
            int hd = eg >> 6, ei = eg & 63;
            *reinterpret_cast<int4*>(vb + (((size_t)(bb * 16 + hd) * 64 + ei) << 10)
                                        + tbase + half * 64 + sub * 8) = v;
        }
    } else {
        unsigned short* dst = which == 0 ? qb : kb;
        #pragma unroll
        for (int p = 0; p < 8; ++p) {
            int seg = (tid >> 3) + p * 32;
            int row = seg >> 1, half = seg & 1, sub = tid & 7;
            int4 v = *reinterpret_cast<const int4*>(smem + row * 130 + half * 64 + sub * 8);
            int colb = n0 + half * 64;
            int hd = (colb & 1023) >> 6;
            int t = tbase + row;
            *reinterpret_cast<int4*>(dst + (((size_t)(bb * 16 + hd) * 1024 + t) << 6) + sub * 8) = v;
        }
    }
}

// ---------------- kernel: out GEMM (MFMA), 2-pass f32 LDS-bounce, fused gate ----------------
__global__ __launch_bounds__(256) void gemm_out_mfma(const unsigned short* __restrict__ A,
                                                     const unsigned short* __restrict__ Bt,
                                                     const float* __restrict__ mod,
                                                     float* __restrict__ out) {
    __shared__ __align__(16) unsigned short smem[16640];
    unsigned short* As = smem;
    unsigned short* Bs = smem + 8192;
    float* fsm = reinterpret_cast<float*>(smem);           // [64][128] f32 = 32 KB
    const int bid = blockIdx.y * 8 + blockIdx.x;
    const int xcd = bid & 7, idx = bid >> 3;
    const int m0 = (xcd * 8 + (idx & 7)) * 128;
    const int n0 = (idx >> 3) * 128;
    const int tid = threadIdx.x;
    const int wid = tid >> 6, lane = tid & 63;
    const int wr = wid >> 1, wc = wid & 1;
    const int lr = lane & 15, g = lane >> 4;
    f32x4 acc[4][4] = {};
    gemm_mainloop(A, Bt, m0, n0, As, Bs, acc);
    #pragma unroll
    for (int hp = 0; hp < 2; ++hp) {
        __syncthreads();
        if (wr == hp) {
            #pragma unroll
            for (int mi = 0; mi < 4; ++mi)
            #pragma unroll
            for (int ni = 0; ni < 4; ++ni)
            #pragma unroll
            for (int r = 0; r < 4; ++r)
                fsm[(mi * 16 + g * 4 + r) * 128 + wc * 64 + ni * 16 + lr] = acc[mi][ni][r];
        }
        __syncthreads();
        #pragma unroll
        for (int p = 0; p < 8; ++p) {
            int unit = tid + p * 256;
            int lrow = unit >> 5, sub = unit & 31;
            float4 v = *reinterpret_cast<const float4*>(fsm + lrow * 128 + sub * 4);
            int row = m0 + hp * 64 + lrow;
            int col = n0 + sub * 4;
            int bb = row >> 10;
            float4 gv = *reinterpret_cast<const float4*>(mod + bb * 3072 + 2048 + col);
            float4 o4;
            o4.x = v.x * gv.x; o4.y = v.y * gv.y; o4.z = v.z * gv.z; o4.w = v.w * gv.w;
            *reinterpret_cast<float4*>(out + (size_t)row * 1024 + col) = o4;
        }
    }
}

// ---------------- kernel: per-row (e=64) LN + RoPE; q pre-scaled by 0.125*log2e ----------------
__global__ __launch_bounds__(256) void lnrope_kernel(unsigned short* __restrict__ qb,
                                                     unsigned short* __restrict__ kb,
                                                     const float* __restrict__ qw,
                                                     const float* __restrict__ kw,
                                                     const float* __restrict__ pos) {
    int gw = blockIdx.x * 4 + (threadIdx.x >> 6);
    int lane = threadIdx.x & 63;
    int half = gw >> 17;                            // 0 = q, 1 = k
    int row = gw & 131071;                          // (b*16+h)*1024 + t
    unsigned short* buf = half ? kb : qb;
    const float* w = half ? kw : qw;
    int t = row & 1023;
    size_t idx = (size_t)row * 64 + lane;
    float xv = bf2f(buf[idx]);
    float mean = wave_sum(xv) * (1.0f / 64.0f);
    float d = xv - mean;
    float var = wave_sum(d * d) * (1.0f / 64.0f);
    float y = d * rsqrtf(var + LN_EPS) * w[lane];
    float pv = (lane < 32) ? pos[t * 32 + lane] : 0.0f;
    float po = __shfl_xor(pv, 1);
    float py = __shfl_xor(y, 1);
    float res = y;
    if (lane < 32)
        res = ((lane & 1) == 0) ? (y * pv - py * po)
                                : (y * po + py * pv);
    // q: fold 1/sqrt(64) and log2(e) (softmax uses exp2)
    buf[idx] = f2bf(half ? res : res * (0.125f * 1.44269504088896f));
}

// ---------------- kernel: MFMA flash attention (V pre-transposed to (B,H,64,T)) ----------------
__global__ __launch_bounds__(256) void attn_mfma_kernel(const unsigned short* __restrict__ qb,
                                                        const unsigned short* __restrict__ kb,
                                                        const unsigned short* __restrict__ vt,
                                                        unsigned short* __restrict__ ob) {
    __shared__ __align__(16) unsigned char smem[24576];
    unsigned short* Ks  = (unsigned short*)smem;            // [64 kv][64 d] swizzled
    unsigned short* Vs  = (unsigned short*)(smem + 8192);   // [64 d][64 kv] swizzled
    unsigned short* paQ = (unsigned short*)(smem + 16384);  // Qs at init, then pa[4][16*64]

    const int bid = blockIdx.x;
    const int swz = (bid & 7) * 256 + (bid >> 3);           // XCD-chunked
    const int bh = swz >> 4;
    const int q0 = (swz & 15) * 64;
    const int b = bh >> 4, hd = bh & 15;
    const size_t base = (size_t)bh << 16;                   // bh * 1024 * 64
    const int tid = threadIdx.x, wid = tid >> 6, lane = tid & 63;
    const int lr = lane & 15, g = lane >> 4;

    #pragma unroll
    for (int p = 0; p < 2; ++p) {
        int r = (tid >> 3) + p * 32;
        int sseg = tid & 7;
        int4 qv = *reinterpret_cast<const int4*>(qb + base + (size_t)(q0 + r) * 64 + sseg * 8);
        *reinterpret_cast<int4*>(paQ + r * 64 + ((sseg ^ (r & 7)) * 8)) = qv;
    }
    __syncthreads();
    bf16x8 af[2];
    #pragma unroll
    for (int ks = 0; ks < 2; ++ks) {
        int row = wid * 16 + lr;
        af[ks] = *reinterpret_cast<const bf16x8*>(paQ + row * 64 + (((ks * 4 + g) ^ (row & 7)) * 8));
    }

    f32x4 acc[4] = {};
    float m_run[4] = {-1e30f, -1e30f, -1e30f, -1e30f};
    float l_run[4] = {0.f, 0.f, 0.f, 0.f};
    unsigned short* pa_w = paQ + wid * 1024;

    for (int cc = 0; cc < 16; ++cc) {
        const int kv0 = cc * 64;
        __syncthreads();
        #pragma unroll
        for (int p = 0; p < 2; ++p) {
            int r = (tid >> 3) + p * 32;
            int sseg = tid & 7;
            int4 kv = *reinterpret_cast<const int4*>(kb + base + (size_t)(kv0 + r) * 64 + sseg * 8);
            *reinterpret_cast<int4*>(Ks + r * 64 + ((sseg ^ (r & 7)) * 8)) = kv;
            // V^T staging: rows are d, stride 1024 along t
            int4 vv = *reinterpret_cast<const int4*>(vt + base + (size_t)r * 1024 + kv0 + sseg * 8);
            *reinterpret_cast<int4*>(Vs + r * 64 + ((sseg ^ (r & 7)) * 8)) = vv;
        }
        __syncthreads();
        f32x4 s[4] = {};
        #pragma unroll
        for (int ks = 0; ks < 2; ++ks) {
            bf16x8 kf[4];
            #pragma unroll
            for (int nt = 0; nt < 4; ++nt) {
                int row = nt * 16 + lr;
                kf[nt] = *reinterpret_cast<const bf16x8*>(Ks + row * 64 + (((ks * 4 + g) ^ (row & 7)) * 8));
            }
            #pragma unroll
            for (int nt = 0; nt < 4; ++nt)
                s[nt] = __builtin_amdgcn_mfma_f32_16x16x32_bf16(af[ks], kf[nt], s[nt], 0, 0, 0);
        }
        #pragma unroll
        for (int r = 0; r < 4; ++r) {
            float mx = fmaxf(fmaxf(s[0][r], s[1][r]), fmaxf(s[2][r], s[3][r]));
            #pragma unroll
            for (int o = 1; o <= 8; o <<= 1) mx = fmaxf(mx, __shfl_xor(mx, o));
            float mn = fmaxf(m_run[r], mx);
            float corr = exp2f(m_run[r] - mn);
            m_run[r] = mn;
            float sum = 0.f;
            #pragma unroll
            for (int nt = 0; nt < 4; ++nt) {
                float e = exp2f(s[nt][r] - mn);
                s[nt][r] = e;
                sum += e;
            }
            #pragma unroll
            for (int o = 1; o <= 8; o <<= 1) sum += __shfl_xor(sum, o);
            l_run[r] = l_run[r] * corr + sum;
            #pragma unroll
            for (int nt = 0; nt < 4; ++nt) acc[nt][r] *= corr;
        }
        #pragma unroll
        for (int nt = 0; nt < 4; ++nt)
        #pragma unroll
        for (int r = 0; r < 4; ++r) {
            int q = g * 4 + r;
            pa_w[q * 64 + (((nt * 2 + (lr >> 3)) ^ (q & 7)) * 8) + (lr & 7)] = f2bf(s[nt][r]);
        }
        #pragma unroll
        for (int ks = 0; ks < 2; ++ks) {
            bf16x8 paf = *reinterpret_cast<const bf16x8*>(pa_w + lr * 64 + (((ks * 4 + g) ^ (lr & 7)) * 8));
            bf16x8 vf[4];
            #pragma unroll
            for (int nt = 0; nt < 4; ++nt) {
                int row = nt * 16 + lr;
                vf[nt] = *reinterpret_cast<const bf16x8*>(Vs + row * 64 + (((ks * 4 + g) ^ (row & 7)) * 8));
            }
            #pragma unroll
            for (int nt = 0; nt < 4; ++nt)
                acc[nt] = __builtin_amdgcn_mfma_f32_16x16x32_bf16(paf, vf[nt], acc[nt], 0, 0, 0);
        }
    }
    float inv[4];
    #pragma unroll
    for (int r = 0; r < 4; ++r) inv[r] = 1.0f / l_run[r];
    #pragma unroll
    for (int nt = 0; nt < 4; ++nt)
    #pragma unroll
    for (int r = 0; r < 4; ++r) {
        int q = q0 + wid * 16 + g * 4 + r;
        int d = hd * 64 + nt * 16 + lr;
        ob[(size_t)(b * 1024 + q) * 1024 + d] = f2bf(acc[nt][r] * inv[r]);
    }
}

extern "C" void kernel_launch(void* const* d_in, const int* in_sizes, int n_in,
                              void* d_out, int out_size, void* d_ws, size_t ws_size,
                              hipStream_t stream) {
    const float* x      = (const float*)d_in[0];
    const float* timep  = (const float*)d_in[1];
    const float* pos    = (const float*)d_in[2];
    const float* mod_w  = (const float*)d_in[3];
    const float* mod_b  = (const float*)d_in[4];
    const float* w_qkv  = (const float*)d_in[5];
    const float* w_out  = (const float*)d_in[6];
    const float* qw     = (const float*)d_in[7];
    const float* kw     = (const float*)d_in[8];
    float* outp = (float*)d_out;                   // f32 (8,1024,1024)

    char* ws = (char*)d_ws;
    float*          modbuf = (float*)ws;                          // 98304 B
    unsigned short* wqkvT  = (unsigned short*)(ws + 98304);       // bf16 [3072][1024]
    unsigned short* woutT  = (unsigned short*)(ws + 6389760);     // bf16 [1024][1024]
    unsigned short* hbuf   = (unsigned short*)(ws + 8486912);     // 16 MB (h, then o)
    unsigned short* qbuf   = hbuf + 8388608;
    unsigned short* kbuf   = qbuf + 8388608;
    unsigned short* vbuf   = kbuf + 8388608;       // v in (B,H,64,T) layout
    unsigned short* obuf   = hbuf;

    transpose_cvt_kernel<<<dim3(96, 32), 256, 0, stream>>>(w_qkv, wqkvT, 1024, 3072);
    transpose_cvt_kernel<<<dim3(32, 32), 256, 0, stream>>>(w_out, woutT, 1024, 1024);
    mod_kernel<<<96, 256, 0, stream>>>(timep, mod_w, mod_b, modbuf);
    ln_mod_kernel<<<8192, 256, 0, stream>>>(x, modbuf, hbuf);
    gemm_qkv_mfma<<<dim3(24, 64), 256, 0, stream>>>(hbuf, wqkvT, qbuf, kbuf, vbuf);
    lnrope_kernel<<<65536, 256, 0, stream>>>(qbuf, kbuf, qw, kw, pos);
    attn_mfma_kernel<<<2048, 256, 0, stream>>>(qbuf, kbuf, vbuf, obuf);
    gemm_out_mfma<<<dim3(8, 64), 256, 0, stream>>>(obuf, woutT, modbuf, outp);
}

// Round 11
// 286.123 us; speedup vs baseline: 8.4674x; 1.0492x over previous
//
#include <hip/hip_runtime.h>

typedef short bf16x8 __attribute__((ext_vector_type(8)));
typedef float f32x4 __attribute__((ext_vector_type(4)));

#define LN_EPS 1e-6f

static __device__ __forceinline__ float bf2f(unsigned short u) {
    union { unsigned int i; float f; } v; v.i = ((unsigned int)u) << 16; return v.f;
}
static __device__ __forceinline__ unsigned short f2bf(float f) {
    union { float ff; unsigned int i; } v; v.ff = f;
    return (unsigned short)((v.i + 0x7FFFu + ((v.i >> 16) & 1u)) >> 16);  // RNE
}
static __device__ __forceinline__ float wave_sum(float v) {
    #pragma unroll
    for (int o = 32; o >= 1; o >>= 1) v += __shfl_xor(v, o);
    return v;
}
// async global->LDS, 16B per lane; LDS dest is wave-uniform base + lane*16
static __device__ __forceinline__ void gl_lds16(const unsigned short* g, unsigned short* l) {
    __builtin_amdgcn_global_load_lds((__attribute__((address_space(1))) void*)g,
                                     (__attribute__((address_space(3))) void*)l,
                                     16, 0, 0);
}

// ---------------- kernel: mod = silu(time) @ mod_w + mod_b  (8 x 3072) ----------------
__global__ __launch_bounds__(256) void mod_kernel(const float* __restrict__ timep,
                                                  const float* __restrict__ mod_w,
                                                  const float* __restrict__ mod_b,
                                                  float* __restrict__ mod) {
    __shared__ float st[1024];
    int b = blockIdx.x / 12;
    int j = (blockIdx.x % 12) * 256 + threadIdx.x;
    for (int i = threadIdx.x; i < 1024; i += 256) {
        float t = timep[b * 1024 + i];
        st[i] = t / (1.0f + __expf(-t));   // silu
    }
    __syncthreads();
    float acc = mod_b[j];
    for (int i = 0; i < 1024; ++i) acc = fmaf(st[i], mod_w[(size_t)i * 3072 + j], acc);
    mod[b * 3072 + j] = acc;
}

// ---------------- kernel: h = LN(x) * (scale+1) + shift  -> bf16 ----------------
__global__ __launch_bounds__(256) void ln_mod_kernel(const float* __restrict__ x,
                                                     const float* __restrict__ mod,
                                                     unsigned short* __restrict__ h) {
    __shared__ float red[8];
    int row = blockIdx.x;              // b*1024 + t
    int b = row >> 10;
    const float4 v = reinterpret_cast<const float4*>(x + (size_t)row * 1024)[threadIdx.x];
    float s  = v.x + v.y + v.z + v.w;
    float ss = v.x * v.x + v.y * v.y + v.z * v.z + v.w * v.w;
    #pragma unroll
    for (int o = 32; o >= 1; o >>= 1) { s += __shfl_xor(s, o); ss += __shfl_xor(ss, o); }
    int wid = threadIdx.x >> 6, lane = threadIdx.x & 63;
    if (lane == 0) { red[wid] = s; red[4 + wid] = ss; }
    __syncthreads();
    float mean = (red[0] + red[1] + red[2] + red[3]) * (1.0f / 1024.0f);
    float var  = (red[4] + red[5] + red[6] + red[7]) * (1.0f / 1024.0f) - mean * mean;
    float rstd = rsqrtf(var + LN_EPS);
    int d = threadIdx.x * 4;
    const float* mb = mod + b * 3072;
    float4 shf = *reinterpret_cast<const float4*>(mb + d);          // shift
    float4 scl = *reinterpret_cast<const float4*>(mb + 1024 + d);   // scale
    ushort4 o;
    o.x = f2bf((v.x - mean) * rstd * (scl.x + 1.0f) + shf.x);
    o.y = f2bf((v.y - mean) * rstd * (scl.y + 1.0f) + shf.y);
    o.z = f2bf((v.z - mean) * rstd * (scl.z + 1.0f) + shf.z);
    o.w = f2bf((v.w - mean) * rstd * (scl.w + 1.0f) + shf.w);
    reinterpret_cast<ushort4*>(h + (size_t)row * 1024)[threadIdx.x] = o;
}

// ---------------- kernel: fp32 [R][C] -> bf16 transposed [C][R] ----------------
__global__ __launch_bounds__(256) void transpose_cvt_kernel(const float* __restrict__ src,
                                                            unsigned short* __restrict__ dst,
                                                            int R, int C) {
    __shared__ unsigned short t[32][33];
    int c0 = blockIdx.x * 32, r0 = blockIdx.y * 32;
    int tx = threadIdx.x & 31, ty = threadIdx.x >> 5;
    #pragma unroll
    for (int i = 0; i < 4; ++i) {
        int r = ty + i * 8;
        t[r][tx] = f2bf(src[(size_t)(r0 + r) * C + c0 + tx]);
    }
    __syncthreads();
    #pragma unroll
    for (int i = 0; i < 4; ++i) {
        int c = ty + i * 8;
        dst[(size_t)(c0 + c) * R + r0 + tx] = t[tx][c];
    }
}

// ---------------- MFMA GEMM main loop (m97 structure): global_load_lds staging ----------------
static __device__ __forceinline__ void gemm_mainloop(const unsigned short* __restrict__ A,
                                                     const unsigned short* __restrict__ Bt,
                                                     int m0, int n0,
                                                     unsigned short* As, unsigned short* Bs,
                                                     f32x4 (&acc)[4][4]) {
    const int tid = threadIdx.x;
    const int wid = tid >> 6, lane = tid & 63;
    const int wr = wid >> 1, wc = wid & 1;
    const int lr = lane & 15, lks = lane >> 4;
    const int gofs = (lane >> 3) * 1024 + (((lane & 7) ^ (lane >> 3)) * 8);
    const unsigned short* Ag = A  + (size_t)(m0 + wid * 32) * 1024 + gofs;
    const unsigned short* Bg = Bt + (size_t)(n0 + wid * 32) * 1024 + gofs;
    unsigned short* AsW = As + wid * 32 * 64;
    unsigned short* BsW = Bs + wid * 32 * 64;
    for (int k0 = 0; k0 < 1024; k0 += 64) {
        __syncthreads();
        #pragma unroll
        for (int j = 0; j < 4; ++j) {
            gl_lds16(Ag + k0 + j * 8192, AsW + j * 512);
            gl_lds16(Bg + k0 + j * 8192, BsW + j * 512);
        }
        __syncthreads();
        #pragma unroll
        for (int ks = 0; ks < 2; ++ks) {
            bf16x8 af[4], bfr[4];
            #pragma unroll
            for (int mi = 0; mi < 4; ++mi) {
                int row = wr * 64 + mi * 16 + lr;
                int ss = (ks * 4 + lks) ^ (row & 7);
                af[mi] = *reinterpret_cast<const bf16x8*>(As + row * 64 + ss * 8);
            }
            #pragma unroll
            for (int ni = 0; ni < 4; ++ni) {
                int row = wc * 64 + ni * 16 + lr;
                int ss = (ks * 4 + lks) ^ (row & 7);
                bfr[ni] = *reinterpret_cast<const bf16x8*>(Bs + row * 64 + ss * 8);
            }
            #pragma unroll
            for (int mi = 0; mi < 4; ++mi)
                #pragma unroll
                for (int ni = 0; ni < 4; ++ni)
                    acc[mi][ni] = __builtin_amdgcn_mfma_f32_16x16x32_bf16(af[mi], bfr[ni], acc[mi][ni], 0, 0, 0);
        }
    }
}

// ---------------- kernel: qkv GEMM (MFMA); q/k scattered (B,H,T,64); v stored TRANSPOSED (B,H,64,T) ----------------
__global__ __launch_bounds__(256) void gemm_qkv_mfma(const unsigned short* __restrict__ A,
                                                     const unsigned short* __restrict__ Bt,
                                                     unsigned short* __restrict__ qb,
                                                     unsigned short* __restrict__ kb,
                                                     unsigned short* __restrict__ vb) {
    __shared__ __align__(16) unsigned short smem[16640];   // As|Bs (16384), bounce uses stride 130
    unsigned short* As = smem;
    unsigned short* Bs = smem + 8192;
    const int bid = blockIdx.y * 24 + blockIdx.x;
    const int xcd = bid & 7, idx = bid >> 3;
    const int m0 = (xcd * 8 + (idx & 7)) * 128;
    const int n0 = (idx >> 3) * 128;
    const int tid = threadIdx.x;
    const int wid = tid >> 6, lane = tid & 63;
    const int wr = wid >> 1, wc = wid & 1;
    const int lr = lane & 15, g = lane >> 4;
    const int which = n0 >> 10;                     // block-uniform: 0=q 1=k 2=v
    f32x4 acc[4][4] = {};
    gemm_mainloop(A, Bt, m0, n0, As, Bs, acc);
    __syncthreads();
    // ---- bounce C tile to LDS (stride 130); v blocks bounce TRANSPOSED ----
    #pragma unroll
    for (int mi = 0; mi < 4; ++mi)
    #pragma unroll
    for (int ni = 0; ni < 4; ++ni)
    #pragma unroll
    for (int r = 0; r < 4; ++r) {
        int row = wr * 64 + mi * 16 + g * 4 + r;
        int col = wc * 64 + ni * 16 + lr;
        if (which == 2) smem[col * 130 + row] = f2bf(acc[mi][ni][r]);
        else            smem[row * 130 + col] = f2bf(acc[mi][ni][r]);
    }
    __syncthreads();
    const int bb = m0 >> 10, tbase = m0 & 1023;
    if (which == 2) {
        // transposed store: 16B along t
        #pragma unroll
        for (int p = 0; p < 8; ++p) {
            int seg = (tid >> 3) + p * 32;          // 0..255
            int erow = seg >> 1, half = seg & 1, sub = tid & 7;
            int4 v = *reinterpret_cast<const int4*>(smem + erow * 130 + half * 64 + sub * 8);
            int eg = (n0 & 1023) + erow;
            int hd = eg >> 6, ei = eg & 63;
            *reinterpret_cast<int4*>(vb + (((size_t)(bb * 16 + hd) * 64 + ei) << 10)
                                        + tbase + half * 64 + sub * 8) = v;
        }
    } else {
        unsigned short* dst = which == 0 ? qb : kb;
        #pragma unroll
        for (int p = 0; p < 8; ++p) {
            int seg = (tid >> 3) + p * 32;
            int row = seg >> 1, half = seg & 1, sub = tid & 7;
            int4 v = *reinterpret_cast<const int4*>(smem + row * 130 + half * 64 + sub * 8);
            int colb = n0 + half * 64;
            int hd = (colb & 1023) >> 6;
            int t = tbase + row;
            *reinterpret_cast<int4*>(dst + (((size_t)(bb * 16 + hd) * 1024 + t) << 6) + sub * 8) = v;
        }
    }
}

// ---------------- kernel: out GEMM (MFMA), 2-pass f32 LDS-bounce, fused gate ----------------
__global__ __launch_bounds__(256) void gemm_out_mfma(const unsigned short* __restrict__ A,
                                                     const unsigned short* __restrict__ Bt,
                                                     const float* __restrict__ mod,
                                                     float* __restrict__ out) {
    __shared__ __align__(16) unsigned short smem[16640];
    unsigned short* As = smem;
    unsigned short* Bs = smem + 8192;
    float* fsm = reinterpret_cast<float*>(smem);           // [64][128] f32 = 32 KB
    const int bid = blockIdx.y * 8 + blockIdx.x;
    const int xcd = bid & 7, idx = bid >> 3;
    const int m0 = (xcd * 8 + (idx & 7)) * 128;
    const int n0 = (idx >> 3) * 128;
    const int tid = threadIdx.x;
    const int wid = tid >> 6, lane = tid & 63;
    const int wr = wid >> 1, wc = wid & 1;
    const int lr = lane & 15, g = lane >> 4;
    f32x4 acc[4][4] = {};
    gemm_mainloop(A, Bt, m0, n0, As, Bs, acc);
    #pragma unroll
    for (int hp = 0; hp < 2; ++hp) {
        __syncthreads();
        if (wr == hp) {
            #pragma unroll
            for (int mi = 0; mi < 4; ++mi)
            #pragma unroll
            for (int ni = 0; ni < 4; ++ni)
            #pragma unroll
            for (int r = 0; r < 4; ++r)
                fsm[(mi * 16 + g * 4 + r) * 128 + wc * 64 + ni * 16 + lr] = acc[mi][ni][r];
        }
        __syncthreads();
        #pragma unroll
        for (int p = 0; p < 8; ++p) {
            int unit = tid + p * 256;
            int lrow = unit >> 5, sub = unit & 31;
            float4 v = *reinterpret_cast<const float4*>(fsm + lrow * 128 + sub * 4);
            int row = m0 + hp * 64 + lrow;
            int col = n0 + sub * 4;
            int bb = row >> 10;
            float4 gv = *reinterpret_cast<const float4*>(mod + bb * 3072 + 2048 + col);
            float4 o4;
            o4.x = v.x * gv.x; o4.y = v.y * gv.y; o4.z = v.z * gv.z; o4.w = v.w * gv.w;
            *reinterpret_cast<float4*>(out + (size_t)row * 1024 + col) = o4;
        }
    }
}

// ---------------- kernel: per-row (e=64) LN + RoPE; q pre-scaled by 0.125*log2e ----------------
__global__ __launch_bounds__(256) void lnrope_kernel(unsigned short* __restrict__ qb,
                                                     unsigned short* __restrict__ kb,
                                                     const float* __restrict__ qw,
                                                     const float* __restrict__ kw,
                                                     const float* __restrict__ pos) {
    int gw = blockIdx.x * 4 + (threadIdx.x >> 6);
    int lane = threadIdx.x & 63;
    int half = gw >> 17;                            // 0 = q, 1 = k
    int row = gw & 131071;                          // (b*16+h)*1024 + t
    unsigned short* buf = half ? kb : qb;
    const float* w = half ? kw : qw;
    int t = row & 1023;
    size_t idx = (size_t)row * 64 + lane;
    float xv = bf2f(buf[idx]);
    float mean = wave_sum(xv) * (1.0f / 64.0f);
    float d = xv - mean;
    float var = wave_sum(d * d) * (1.0f / 64.0f);
    float y = d * rsqrtf(var + LN_EPS) * w[lane];
    float pv = (lane < 32) ? pos[t * 32 + lane] : 0.0f;
    float po = __shfl_xor(pv, 1);
    float py = __shfl_xor(y, 1);
    float res = y;
    if (lane < 32)
        res = ((lane & 1) == 0) ? (y * pv - py * po)
                                : (y * po + py * pv);
    // q: fold 1/sqrt(64) and log2(e) (softmax uses exp2)
    buf[idx] = f2bf(half ? res : res * (0.125f * 1.44269504088896f));
}

// ---------------- kernel: MFMA flash attention v3 (KVBLK=128, defer-max, lane-partial l) ----------------
__global__ __launch_bounds__(256) void attn_mfma_kernel(const unsigned short* __restrict__ qb,
                                                        const unsigned short* __restrict__ kb,
                                                        const unsigned short* __restrict__ vt,
                                                        unsigned short* __restrict__ ob) {
    __shared__ __align__(16) unsigned char smem[49152];
    unsigned short* Ks  = (unsigned short*)smem;            // [128 kv][64 d] swizzled
    unsigned short* Vs  = (unsigned short*)(smem + 16384);  // [64 d][128 kv] swizzled
    unsigned short* paQ = (unsigned short*)(smem + 32768);  // Qs at init, then pa[4][16][128]

    const int bid = blockIdx.x;
    const int swz = (bid & 7) * 256 + (bid >> 3);           // XCD-chunked
    const int bh = swz >> 4;
    const int q0 = (swz & 15) * 64;
    const int b = bh >> 4, hd = bh & 15;
    const size_t base = (size_t)bh << 16;                   // bh * 1024 * 64
    const int tid = threadIdx.x, wid = tid >> 6, lane = tid & 63;
    const int lr = lane & 15, g = lane >> 4;

    // ---- stage Q block (swizzled), load A-fragments to registers ----
    #pragma unroll
    for (int p = 0; p < 2; ++p) {
        int r = (tid >> 3) + p * 32;
        int sseg = tid & 7;
        int4 qv = *reinterpret_cast<const int4*>(qb + base + (size_t)(q0 + r) * 64 + sseg * 8);
        *reinterpret_cast<int4*>(paQ + r * 64 + ((sseg ^ (r & 7)) * 8)) = qv;
    }
    __syncthreads();
    bf16x8 af[2];
    #pragma unroll
    for (int ks = 0; ks < 2; ++ks) {
        int row = wid * 16 + lr;
        af[ks] = *reinterpret_cast<const bf16x8*>(paQ + row * 64 + (((ks * 4 + g) ^ (row & 7)) * 8));
    }

    f32x4 acc[4] = {};
    float m_run[4] = {-1e30f, -1e30f, -1e30f, -1e30f};
    float l_par[4] = {0.f, 0.f, 0.f, 0.f};     // lane-partial denominators
    unsigned short* pa_w = paQ + wid * 2048;   // wave-private P [16 q][128 kv] swizzled

    for (int cc = 0; cc < 8; ++cc) {
        const int kv0 = cc * 128;
        __syncthreads();
        // ---- stage K chunk [128 kv][64 d] ----
        #pragma unroll
        for (int p = 0; p < 4; ++p) {
            int r = (tid >> 3) + p * 32;
            int sseg = tid & 7;
            int4 kv = *reinterpret_cast<const int4*>(kb + base + (size_t)(kv0 + r) * 64 + sseg * 8);
            *reinterpret_cast<int4*>(Ks + r * 64 + ((sseg ^ (r & 7)) * 8)) = kv;
        }
        // ---- stage V^T chunk [64 d][128 kv] ----
        #pragma unroll
        for (int p = 0; p < 4; ++p) {
            int idx = tid + p * 256;
            int row = idx >> 4, seg = idx & 15;
            int4 vv = *reinterpret_cast<const int4*>(vt + base + (size_t)row * 1024 + kv0 + seg * 8);
            *reinterpret_cast<int4*>(Vs + row * 128 + ((seg ^ (row & 7)) * 8)) = vv;
        }
        __syncthreads();
        // ---- QK^T: S[16 q][128 kv] per wave (16 MFMAs) ----
        f32x4 s[8];
        #pragma unroll
        for (int nt = 0; nt < 8; ++nt) s[nt] = (f32x4){0.f, 0.f, 0.f, 0.f};
        #pragma unroll
        for (int ks = 0; ks < 2; ++ks) {
            #pragma unroll
            for (int nt = 0; nt < 8; ++nt) {
                int row = nt * 16 + lr;
                bf16x8 kf = *reinterpret_cast<const bf16x8*>(Ks + row * 64 + (((ks * 4 + g) ^ (row & 7)) * 8));
                s[nt] = __builtin_amdgcn_mfma_f32_16x16x32_bf16(af[ks], kf, s[nt], 0, 0, 0);
            }
        }
        // ---- online softmax: defer-max + lane-partial l ----
        float mx[4];
        #pragma unroll
        for (int r = 0; r < 4; ++r) {
            float m = s[0][r];
            #pragma unroll
            for (int nt = 1; nt < 8; ++nt) m = fmaxf(m, s[nt][r]);
            #pragma unroll
            for (int o = 1; o <= 8; o <<= 1) m = fmaxf(m, __shfl_xor(m, o));
            mx[r] = m;
        }
        int need = 0;
        #pragma unroll
        for (int r = 0; r < 4; ++r) need |= (mx[r] - m_run[r] > 8.0f) ? 1 : 0;
        if (__any(need)) {
            #pragma unroll
            for (int r = 0; r < 4; ++r) {
                float mn = fmaxf(m_run[r], mx[r]);
                float corr = exp2f(m_run[r] - mn);
                m_run[r] = mn;
                l_par[r] *= corr;
                #pragma unroll
                for (int nt = 0; nt < 4; ++nt) acc[nt][r] *= corr;
            }
        }
        #pragma unroll
        for (int r = 0; r < 4; ++r)
        #pragma unroll
        for (int nt = 0; nt < 8; ++nt) {
            float e = exp2f(s[nt][r] - m_run[r]);
            s[nt][r] = e;
            l_par[r] += e;
        }
        // ---- write P (bf16, single-op cvt) to wave-private LDS in A-fragment layout ----
        #pragma unroll
        for (int nt = 0; nt < 8; ++nt)
        #pragma unroll
        for (int r = 0; r < 4; ++r) {
            int q = g * 4 + r;
            unsigned int pk;
            asm("v_cvt_pk_bf16_f32 %0, %1, %2" : "=v"(pk) : "v"(s[nt][r]), "v"(0.f));
            pa_w[q * 128 + (((nt * 2 + (lr >> 3)) ^ (q & 7)) * 8) + (lr & 7)] = (unsigned short)pk;
        }
        // ---- PV: O += P @ V (16 MFMAs) ----
        #pragma unroll
        for (int ks = 0; ks < 4; ++ks) {
            bf16x8 paf = *reinterpret_cast<const bf16x8*>(pa_w + lr * 128 + (((ks * 4 + g) ^ (lr & 7)) * 8));
            #pragma unroll
            for (int nt = 0; nt < 4; ++nt) {
                int row = nt * 16 + lr;
                bf16x8 vf = *reinterpret_cast<const bf16x8*>(Vs + row * 128 + (((ks * 4 + g) ^ (row & 7)) * 8));
                acc[nt] = __builtin_amdgcn_mfma_f32_16x16x32_bf16(paf, vf, acc[nt], 0, 0, 0);
            }
        }
    }
    // ---- final: reduce lane-partial l, O/l, write (B, T, H*64) ----
    float inv[4];
    #pragma unroll
    for (int r = 0; r < 4; ++r) {
        float l = l_par[r];
        #pragma unroll
        for (int o = 1; o <= 8; o <<= 1) l += __shfl_xor(l, o);
        inv[r] = 1.0f / l;
    }
    #pragma unroll
    for (int nt = 0; nt < 4; ++nt)
    #pragma unroll
    for (int r = 0; r < 4; ++r) {
        int q = q0 + wid * 16 + g * 4 + r;
        int d = hd * 64 + nt * 16 + lr;
        ob[(size_t)(b * 1024 + q) * 1024 + d] = f2bf(acc[nt][r] * inv[r]);
    }
}

extern "C" void kernel_launch(void* const* d_in, const int* in_sizes, int n_in,
                              void* d_out, int out_size, void* d_ws, size_t ws_size,
                              hipStream_t stream) {
    const float* x      = (const float*)d_in[0];
    const float* timep  = (const float*)d_in[1];
    const float* pos    = (const float*)d_in[2];
    const float* mod_w  = (const float*)d_in[3];
    const float* mod_b  = (const float*)d_in[4];
    const float* w_qkv  = (const float*)d_in[5];
    const float* w_out  = (const float*)d_in[6];
    const float* qw     = (const float*)d_in[7];
    const float* kw     = (const float*)d_in[8];
    float* outp = (float*)d_out;                   // f32 (8,1024,1024)

    char* ws = (char*)d_ws;
    float*          modbuf = (float*)ws;                          // 98304 B
    unsigned short* wqkvT  = (unsigned short*)(ws + 98304);       // bf16 [3072][1024]
    unsigned short* woutT  = (unsigned short*)(ws + 6389760);     // bf16 [1024][1024]
    unsigned short* hbuf   = (unsigned short*)(ws + 8486912);     // 16 MB (h, then o)
    unsigned short* qbuf   = hbuf + 8388608;
    unsigned short* kbuf   = qbuf + 8388608;
    unsigned short* vbuf   = kbuf + 8388608;       // v in (B,H,64,T) layout
    unsigned short* obuf   = hbuf;

    transpose_cvt_kernel<<<dim3(96, 32), 256, 0, stream>>>(w_qkv, wqkvT, 1024, 3072);
    transpose_cvt_kernel<<<dim3(32, 32), 256, 0, stream>>>(w_out, woutT, 1024, 1024);
    mod_kernel<<<96, 256, 0, stream>>>(timep, mod_w, mod_b, modbuf);
    ln_mod_kernel<<<8192, 256, 0, stream>>>(x, modbuf, hbuf);
    gemm_qkv_mfma<<<dim3(24, 64), 256, 0, stream>>>(hbuf, wqkvT, qbuf, kbuf, vbuf);
    lnrope_kernel<<<65536, 256, 0, stream>>>(qbuf, kbuf, qw, kw, pos);
    attn_mfma_kernel<<<2048, 256, 0, stream>>>(qbuf, kbuf, vbuf, obuf);
    gemm_out_mfma<<<dim3(8, 64), 256, 0, stream>>>(obuf, woutT, modbuf, outp);
}